// Round 8
// baseline (179.873 us; speedup 1.0000x reference)
//
#include <hip/hip_runtime.h>
#include <stdint.h>

#define NCLS   15
#define NTH    18
#define BATCH  16
#define NANCH  49104
#define KTOP   1000
#define NWORDS 16   // 16*64 = 1024 >= 1000
#define NBIN   32768
#define BSHIFT 15
#define CAND   2048

__device__ __forceinline__ float sigmoidf(float x) {
    return 1.0f / (1.0f + expf(-x));
}

__device__ __forceinline__ void levelOf(int i, int& lvl, int& h, int& s, int& pos) {
    if (i < 36864)      { lvl = 0; h = 192; s = 8;   pos = i; }
    else if (i < 46080) { lvl = 1; h = 96;  s = 16;  pos = i - 36864; }
    else if (i < 48384) { lvl = 2; h = 48;  s = 32;  pos = i - 46080; }
    else if (i < 48960) { lvl = 3; h = 24;  s = 64;  pos = i - 48384; }
    else                { lvl = 4; h = 12;  s = 128; pos = i - 48960; }
}

__device__ __forceinline__ unsigned long long shflxor_u64(unsigned long long v, int m) {
    int lo = __shfl_xor((int)(unsigned int)(v & 0xFFFFFFFFull), m);
    int hi = __shfl_xor((int)(unsigned int)(v >> 32), m);
    return ((unsigned long long)(unsigned int)hi << 32) | (unsigned long long)(unsigned int)lo;
}

__device__ __forceinline__ unsigned long long readlane_u64(unsigned long long v, int lane) {
    unsigned int lo = (unsigned int)__builtin_amdgcn_readlane((int)(unsigned int)(v & 0xFFFFFFFFull), lane);
    unsigned int hi = (unsigned int)__builtin_amdgcn_readlane((int)(unsigned int)(v >> 32), lane);
    return ((unsigned long long)hi << 32) | (unsigned long long)lo;
}

__device__ __forceinline__ unsigned long long readfirst_u64(unsigned long long v) {
    unsigned int lo = (unsigned int)__builtin_amdgcn_readfirstlane((int)(unsigned int)(v & 0xFFFFFFFFull));
    unsigned int hi = (unsigned int)__builtin_amdgcn_readfirstlane((int)(unsigned int)(v >> 32));
    return ((unsigned long long)hi << 32) | (unsigned long long)lo;
}

// ---- Kernel 1: per-anchor score = sigmoid(max logit), float4 ---------------------
__global__ __launch_bounds__(256) void k_scores(
    const float* __restrict__ c0, const float* __restrict__ c1,
    const float* __restrict__ c2, const float* __restrict__ c3,
    const float* __restrict__ c4,
    float* __restrict__ scores, unsigned int* __restrict__ hist)
{
    __shared__ unsigned int lh[NBIN / 2];          // 64 KB, 16-bit packed counts
    const int b = blockIdx.y;
    for (int i = threadIdx.x; i < NBIN / 2; i += 256) lh[i] = 0u;
    __syncthreads();

    #pragma unroll
    for (int r = 0; r < 2; ++r) {
        int f4 = blockIdx.x * 512 + r * 256 + threadIdx.x;
        if (f4 < NANCH / 4) {
            int i = f4 * 4;
            int lvl, h, s, pos;
            levelOf(i, lvl, h, s, pos);
            int hh = h * h;
            const float* cp = (lvl == 0) ? c0 : (lvl == 1) ? c1 : (lvl == 2) ? c2
                              : (lvl == 3) ? c3 : c4;
            const float* base = cp + (size_t)b * NCLS * hh + pos;
            float4 mx = make_float4(-1e30f, -1e30f, -1e30f, -1e30f);
            #pragma unroll
            for (int c = 0; c < NCLS; ++c) {
                float4 v = *(const float4*)(base + (size_t)c * hh);
                mx.x = fmaxf(mx.x, v.x); mx.y = fmaxf(mx.y, v.y);
                mx.z = fmaxf(mx.z, v.z); mx.w = fmaxf(mx.w, v.w);
            }
            float4 sc = make_float4(sigmoidf(mx.x), sigmoidf(mx.y),
                                    sigmoidf(mx.z), sigmoidf(mx.w));
            *(float4*)(scores + (size_t)b * NANCH + i) = sc;
            unsigned int bin;
            bin = __float_as_uint(sc.x) >> BSHIFT;
            atomicAdd(&lh[bin >> 1], 1u << ((bin & 1) << 4));
            bin = __float_as_uint(sc.y) >> BSHIFT;
            atomicAdd(&lh[bin >> 1], 1u << ((bin & 1) << 4));
            bin = __float_as_uint(sc.z) >> BSHIFT;
            atomicAdd(&lh[bin >> 1], 1u << ((bin & 1) << 4));
            bin = __float_as_uint(sc.w) >> BSHIFT;
            atomicAdd(&lh[bin >> 1], 1u << ((bin & 1) << 4));
        }
    }
    __syncthreads();

    unsigned int* hb = hist + (size_t)b * NBIN;
    for (int wd = threadIdx.x; wd < NBIN / 2; wd += 256) {
        unsigned int v = lh[wd];
        if (v) {
            unsigned int lo = v & 0xFFFFu, hi = v >> 16;
            if (lo) atomicAdd(&hb[wd * 2], lo);
            if (hi) atomicAdd(&hb[wd * 2 + 1], hi);
        }
    }
}

// ---- Kernel 2a: find threshold bin per batch (K-th largest), parallel scan ------
__global__ __launch_bounds__(256) void k_findT(
    const unsigned int* __restrict__ hist, int* __restrict__ tbin)
{
    int b = blockIdx.x;
    int tid = threadIdx.x;
    const unsigned int* hb = hist + (size_t)b * NBIN;
    __shared__ unsigned int sc[256];
    __shared__ unsigned int fsc[128];
    __shared__ int s_c, s_t;

    unsigned int s = 0;
    const uint4* hv = (const uint4*)(hb + (size_t)tid * 128);
    #pragma unroll 8
    for (int k = 0; k < 32; ++k) {
        uint4 v = hv[k];
        s += v.x + v.y + v.z + v.w;
    }
    sc[tid] = s;
    if (tid == 0) { s_c = 0; s_t = 0; }
    __syncthreads();
    for (int d = 1; d < 256; d <<= 1) {
        unsigned int add = (tid + d < 256) ? sc[tid + d] : 0;
        __syncthreads();
        sc[tid] += add;
        __syncthreads();
    }
    if (sc[tid] >= (unsigned int)KTOP && (tid == 255 || sc[tid + 1] < (unsigned int)KTOP))
        s_c = tid;
    __syncthreads();
    int c = s_c;
    unsigned int hi = (c < 255) ? sc[c + 1] : 0;
    if (tid < 128) fsc[tid] = hb[c * 128 + tid];
    __syncthreads();
    for (int d = 1; d < 128; d <<= 1) {
        unsigned int add = (tid < 128 && tid + d < 128) ? fsc[tid + d] : 0;
        __syncthreads();
        if (tid < 128) fsc[tid] += add;
        __syncthreads();
    }
    if (tid < 128 && hi + fsc[tid] >= (unsigned int)KTOP &&
        (tid == 127 || hi + fsc[tid + 1] < (unsigned int)KTOP))
        s_t = tid;
    __syncthreads();
    if (tid == 0) tbin[b] = c * 128 + s_t;
}

// ---- Kernel 2b: compact candidates — block-aggregated, padded counters ----------
__global__ __launch_bounds__(256) void k_compact(
    const float* __restrict__ scores, const int* __restrict__ tbin,
    int* __restrict__ cnt, unsigned long long* __restrict__ cand)
{
    const int b = blockIdx.y;
    const int t4 = blockIdx.x * 256 + threadIdx.x;   // float4 index within batch
    __shared__ int lcnt;
    __shared__ int lbase;
    if (threadIdx.x == 0) lcnt = 0;
    __syncthreads();

    const int T = tbin[b];
    const bool in = (t4 < NANCH / 4);
    float4 v = make_float4(0.f, 0.f, 0.f, 0.f);
    if (in) v = *(const float4*)(scores + (size_t)b * NANCH + 4 * (size_t)t4);
    unsigned int bits[4] = { __float_as_uint(v.x), __float_as_uint(v.y),
                             __float_as_uint(v.z), __float_as_uint(v.w) };
    int rank[4];
    #pragma unroll
    for (int k = 0; k < 4; ++k) {
        bool pass = in && ((int)(bits[k] >> BSHIFT) >= T);
        rank[k] = pass ? atomicAdd(&lcnt, 1) : -1;
    }
    __syncthreads();
    if (threadIdx.x == 0) lbase = atomicAdd(&cnt[b * 16], lcnt);
    __syncthreads();
    const int base = lbase;
    #pragma unroll
    for (int k = 0; k < 4; ++k) {
        if (rank[k] >= 0) {
            int p = base + rank[k];
            if (p < CAND) {
                unsigned int idx = 4u * (unsigned int)t4 + (unsigned int)k;
                cand[(size_t)b * CAND + p] =
                    ((unsigned long long)bits[k] << 32) |
                    (unsigned long long)(0xFFFFFFFFu - idx);
            }
        }
    }
}

// ---- Kernel 2c: per-batch bitonic sort of candidates, emit exact top-K ----------
__global__ __launch_bounds__(1024) void k_sortk(
    const unsigned long long* __restrict__ cand, const int* __restrict__ cnt,
    float* __restrict__ tsc, int* __restrict__ tix)
{
    int b = blockIdx.x;
    int tid = threadIdx.x;
    __shared__ unsigned long long keys[CAND];
    int n = cnt[b * 16]; if (n > CAND) n = CAND;
    for (int i = tid; i < CAND; i += 1024)
        keys[i] = (i < n) ? cand[(size_t)b * CAND + i] : 0ull;
    __syncthreads();
    for (int sz = 2; sz <= CAND; sz <<= 1) {
        for (int st = sz >> 1; st > 0; st >>= 1) {
            for (int i = tid; i < CAND; i += 1024) {
                int j = i ^ st;
                if (j > i) {
                    unsigned long long a = keys[i], c = keys[j];
                    bool desc = ((i & sz) == 0);
                    if (desc ? (a < c) : (a > c)) { keys[i] = c; keys[j] = a; }
                }
            }
            __syncthreads();
        }
    }
    if (tid < KTOP) {
        unsigned long long key = keys[tid];
        tsc[b * KTOP + tid] = __uint_as_float((unsigned int)(key >> 32));
        tix[b * KTOP + tid] = (int)(0xFFFFFFFFu - (unsigned int)(key & 0xFFFFFFFFull));
    }
}

// ---- Kernel 3: decode boxes + exact class argmax for selected anchors -----------
__global__ __launch_bounds__(256) void k_decode(
    const float* __restrict__ c0, const float* __restrict__ c1,
    const float* __restrict__ c2, const float* __restrict__ c3,
    const float* __restrict__ c4,
    const float* __restrict__ r0, const float* __restrict__ r1,
    const float* __restrict__ r2, const float* __restrict__ r3,
    const float* __restrict__ r4,
    const float* __restrict__ t0, const float* __restrict__ t1,
    const float* __restrict__ t2, const float* __restrict__ t3,
    const float* __restrict__ t4,
    const float* __restrict__ q0, const float* __restrict__ q1,
    const float* __restrict__ q2, const float* __restrict__ q3,
    const float* __restrict__ q4,
    const int* __restrict__ tix, float* __restrict__ boxes, int* __restrict__ clstop)
{
    int g = blockIdx.x * 256 + threadIdx.x;
    if (g >= BATCH * KTOP) return;
    int b = g / KTOP;
    int idx = tix[g];
    int lvl, h, s, pos;
    levelOf(idx, lvl, h, s, pos);
    int y = pos / h, x = pos - y * h;
    int hh = h * h;
    const float* cp = (lvl == 0) ? c0 : (lvl == 1) ? c1 : (lvl == 2) ? c2 : (lvl == 3) ? c3 : c4;
    const float* rp = (lvl == 0) ? r0 : (lvl == 1) ? r1 : (lvl == 2) ? r2 : (lvl == 3) ? r3 : r4;
    const float* tp = (lvl == 0) ? t0 : (lvl == 1) ? t1 : (lvl == 2) ? t2 : (lvl == 3) ? t3 : t4;
    const float* qp = (lvl == 0) ? q0 : (lvl == 1) ? q1 : (lvl == 2) ? q2 : (lvl == 3) ? q3 : q4;
    int off = y * h + x;

    const float* cb = cp + (size_t)b * NCLS * hh + off;
    float bestc = -1e30f; int bc = 0;
    #pragma unroll
    for (int c = 0; c < NCLS; ++c) {
        float v = sigmoidf(cb[(size_t)c * hh]);
        if (v > bestc) { bestc = v; bc = c; }
    }
    clstop[g] = bc + 1;

    const float* tb = tp + (size_t)b * NTH * hh + off;
    float best = -1e30f; int bt = 0;
    #pragma unroll
    for (int c = 0; c < NTH; ++c) {
        float v = sigmoidf(tb[(size_t)c * hh]);
        if (v > best) { best = v; bt = c; }
    }
    float theta = (float)(bt + 1) * 10.0f + qp[(size_t)b * hh + off];

    const float* rb = rp + (size_t)b * 5 * hh + off;
    float fs = (float)s;
    float rr0 = rb[0] * fs;
    float rr1 = rb[(size_t)hh] * fs;
    float rr2 = rb[(size_t)2 * hh] * fs;
    float rr3 = rb[(size_t)3 * hh] * fs;
    float cx = (float)(x * s + (s >> 1));
    float cy = (float)(y * s + (s >> 1));
    float* op = boxes + (size_t)g * 5;
    op[0] = cx - rr0;
    op[1] = cy - rr1;
    op[2] = cx + rr2;
    op[3] = cy + rr3;
    op[4] = theta;
}

// ---- Kernel 4a: suppression bitmask, ROW-major [b][1024][16] ---------------------
__global__ __launch_bounds__(256) void k_mask(
    const float* __restrict__ boxes, unsigned long long* __restrict__ mask)
{
    int b = blockIdx.x;
    __shared__ float bx1[KTOP], by1[KTOP], bx2[KTOP], by2[KTOP], bar[KTOP];
    for (int r = threadIdx.x; r < KTOP; r += 256) {
        const float* p = boxes + ((size_t)(b * KTOP + r)) * 5;
        float x1 = p[0], y1 = p[1], x2 = p[2], y2 = p[3];
        bx1[r] = x1; by1[r] = y1; bx2[r] = x2; by2[r] = y2;
        bar[r] = fmaxf(x2 - x1, 0.0f) * fmaxf(y2 - y1, 0.0f);
    }
    __syncthreads();
    int i = (blockIdx.y << 4) + (threadIdx.x >> 4);
    int w = threadIdx.x & 15;
    int j0 = w << 6;
    int lo = (j0 > i + 1) ? j0 : (i + 1);
    int hi = (j0 + 64 < KTOP) ? (j0 + 64) : KTOP;
    unsigned long long m = 0ull;
    if (i < KTOP && lo < hi) {
        float x1 = bx1[i], y1 = by1[i], x2 = bx2[i], y2 = by2[i], ai = bar[i];
        for (int j = lo; j < hi; ++j) {
            float iw = fminf(x2, bx2[j]) - fmaxf(x1, bx1[j]);
            iw = fmaxf(iw, 0.0f);
            float ih = fminf(y2, by2[j]) - fmaxf(y1, by1[j]);
            ih = fmaxf(ih, 0.0f);
            float inter = iw * ih;
            float u = ai + bar[j] - inter;
            float iou = inter / fmaxf(u, 1e-8f);
            if (iou > 0.3f) m |= (1ull << (j - j0));
        }
    }
    mask[(((size_t)b * 1024 + i) << 4) + w] = m;
}

// ---- Kernel 4b: greedy NMS — wave-uniform SCALAR chain (readlane, no LDS) -------
// The greedy recurrence is identical in all lanes: force it scalar so the
// compiler emits SALU (s_and_b64/s_or_b64, ~1cyc) with readlane feeding the
// per-box diag word from VGPRs — no LDS/scratch latency in the chain.
__global__ __launch_bounds__(64) void k_nms(
    const unsigned long long* __restrict__ mask,   // [b][1024][16]
    const float* __restrict__ tsc, const int* __restrict__ clstop,
    const float* __restrict__ boxes, float* __restrict__ out)
{
    const int b = blockIdx.x;
    const int l = threadIdx.x;

    unsigned long long vw[NWORDS];
    #pragma unroll
    for (int w = 0; w < NWORDS; ++w) {
        int i = (w << 6) + l;
        bool v = (i < KTOP) && (tsc[b * KTOP + i] >= 0.05f);
        vw[w] = __ballot(v);
    }

    unsigned long long part[NWORDS];
    #pragma unroll
    for (int w = 0; w < NWORDS; ++w) part[w] = 0ull;

    unsigned long long keepw[NWORDS];

    #pragma unroll
    for (int w = 0; w < NWORDS; ++w) {
        const int base = w << 6;
        // lane l owns row base+l; load its words w..15 (contiguous 16B vectors)
        const unsigned long long* rp = mask + (((size_t)b * 1024 + base + l) << 4);
        unsigned long long row[NWORDS];
        #pragma unroll
        for (int p = (w >> 1); p < 8; ++p) {
            ulonglong2 v = *(const ulonglong2*)(rp + (p << 1));
            row[p * 2] = v.x; row[p * 2 + 1] = v.y;
        }
        const unsigned long long rowword = row[w];   // lane l = diag word of row base+l

        // rem word for this phase: butterfly-OR of per-lane partials -> uniform
        unsigned long long remv = part[w];
        remv |= shflxor_u64(remv, 1);
        remv |= shflxor_u64(remv, 2);
        remv |= shflxor_u64(remv, 4);
        remv |= shflxor_u64(remv, 8);
        remv |= shflxor_u64(remv, 16);
        remv |= shflxor_u64(remv, 32);
        unsigned long long remw  = readfirst_u64(remv);
        unsigned long long valid = readfirst_u64(vw[w]);

        // scalar greedy chain; readlane pulls d[jj] from lane jj's rowword
        unsigned long long keptm = 0ull;
        #pragma unroll
        for (int jj = 0; jj < 64; ++jj) {
            unsigned long long djj = readlane_u64(rowword, jj);
            unsigned long long take = ((valid & ~remw) >> jj) & 1ull;
            keptm |= take << jj;
            remw |= djj & (0ull - take);
        }
        keepw[w] = keptm;

        // lane-local: kept rows OR their future words into this lane's partials
        unsigned long long sel = 0ull - ((keptm >> l) & 1ull);
        #pragma unroll
        for (int w2 = w + 1; w2 < NWORDS; ++w2)
            part[w2] |= row[w2] & sel;
    }

    // fused masked output write
    #pragma unroll
    for (int w = 0; w < NWORDS; ++w) {
        int i = (w << 6) + l;
        if (i < KTOP) {
            int g = b * KTOP + i;
            float fk = (float)((keepw[w] >> l) & 1ull);
            out[g] = tsc[g] * fk;
            out[BATCH * KTOP + g] = (float)clstop[g] * fk;
            const float* bp = boxes + (size_t)g * 5;
            float* op = out + 2 * BATCH * KTOP + (size_t)g * 5;
            op[0] = bp[0] * fk;
            op[1] = bp[1] * fk;
            op[2] = bp[2] * fk;
            op[3] = bp[3] * fk;
            op[4] = bp[4] * fk;
        }
    }
}

extern "C" void kernel_launch(void* const* d_in, const int* in_sizes, int n_in,
                              void* d_out, int out_size, void* d_ws, size_t ws_size,
                              hipStream_t stream) {
    const float* c0 = (const float*)d_in[0];
    const float* c1 = (const float*)d_in[1];
    const float* c2 = (const float*)d_in[2];
    const float* c3 = (const float*)d_in[3];
    const float* c4 = (const float*)d_in[4];
    const float* r0 = (const float*)d_in[5];
    const float* r1 = (const float*)d_in[6];
    const float* r2 = (const float*)d_in[7];
    const float* r3 = (const float*)d_in[8];
    const float* r4 = (const float*)d_in[9];
    const float* t0 = (const float*)d_in[10];
    const float* t1 = (const float*)d_in[11];
    const float* t2 = (const float*)d_in[12];
    const float* t3 = (const float*)d_in[13];
    const float* t4 = (const float*)d_in[14];
    const float* q0 = (const float*)d_in[15];
    const float* q1 = (const float*)d_in[16];
    const float* q2 = (const float*)d_in[17];
    const float* q3 = (const float*)d_in[18];
    const float* q4 = (const float*)d_in[19];

    // Workspace layout, total 5,753,920 B. Aliases safe by stream order:
    //   hist (k_scores→k_findT) aliases mask (k_mask→k_nms)   [findT before mask]
    //   cand (k_compact→k_sortk) aliases boxes (k_decode→...) [sortk before decode]
    char* ws = (char*)d_ws;
    float*              scores  = (float*)(ws + 0);          // 3,142,656
    float*              tsc     = (float*)(ws + 3142656);    //    64,000
    int*                tix     = (int*)(ws + 3206656);      //    64,000
    float*              boxes   = (float*)(ws + 3270656);    //   320,000
    unsigned long long* cand    = (unsigned long long*)(ws + 3270656); // 262,144 alias
    int*                clstop  = (int*)(ws + 3590656);      //    64,000
    unsigned long long* mask    = (unsigned long long*)(ws + 3654656); // 2,097,152
    unsigned int*       hist    = (unsigned int*)(ws + 3654656);       // alias
    int*                tcnt    = (int*)(ws + 5751808);      //     1,024 (16 x 64B)
    int*                tbin    = (int*)(ws + 5752832);      //        64
    float*              out     = (float*)d_out;

    // zero hist + tcnt (contiguous: 2,097,152 + 1,024)
    hipMemsetAsync(ws + 3654656, 0, 2098176, stream);

    k_scores<<<dim3(24, BATCH), 256, 0, stream>>>(
        c0, c1, c2, c3, c4, scores, hist);
    k_findT<<<BATCH, 256, 0, stream>>>(hist, tbin);
    k_compact<<<dim3(48, BATCH), 256, 0, stream>>>(scores, tbin, tcnt, cand);
    k_sortk<<<BATCH, 1024, 0, stream>>>(cand, tcnt, tsc, tix);
    k_decode<<<(BATCH * KTOP + 255) / 256, 256, 0, stream>>>(
        c0, c1, c2, c3, c4,
        r0, r1, r2, r3, r4, t0, t1, t2, t3, t4, q0, q1, q2, q3, q4,
        tix, boxes, clstop);
    k_mask<<<dim3(BATCH, 64), 256, 0, stream>>>(boxes, mask);
    k_nms<<<BATCH, 64, 0, stream>>>(mask, tsc, clstop, boxes, out);
}

// Round 9
// 145.111 us; speedup vs baseline: 1.2396x; 1.2396x over previous
//
#include <hip/hip_runtime.h>
#include <stdint.h>

#define NCLS   15
#define NTH    18
#define BATCH  16
#define NANCH  49104
#define KTOP   1000
#define NWORDS 16   // 16*64 = 1024 >= 1000
#define NBIN   32768
#define BSHIFT 15
#define CAND   2048

__device__ __forceinline__ float sigmoidf(float x) {
    return 1.0f / (1.0f + expf(-x));
}

__device__ __forceinline__ void levelOf(int i, int& lvl, int& h, int& s, int& pos) {
    if (i < 36864)      { lvl = 0; h = 192; s = 8;   pos = i; }
    else if (i < 46080) { lvl = 1; h = 96;  s = 16;  pos = i - 36864; }
    else if (i < 48384) { lvl = 2; h = 48;  s = 32;  pos = i - 46080; }
    else if (i < 48960) { lvl = 3; h = 24;  s = 64;  pos = i - 48384; }
    else                { lvl = 4; h = 12;  s = 128; pos = i - 48960; }
}

__device__ __forceinline__ unsigned long long shfl_u64(unsigned long long v, int src) {
    int lo = __shfl((int)(unsigned int)(v & 0xFFFFFFFFull), src);
    int hi = __shfl((int)(unsigned int)(v >> 32), src);
    return ((unsigned long long)(unsigned int)hi << 32) | (unsigned long long)(unsigned int)lo;
}

__device__ __forceinline__ void atomicOr64Shared(unsigned long long* p, unsigned long long v) {
    unsigned int* q = (unsigned int*)p;
    unsigned int lo = (unsigned int)v;
    unsigned int hi = (unsigned int)(v >> 32);
    if (lo) atomicOr(q, lo);
    if (hi) atomicOr(q + 1, hi);
}

// ---- Kernel 1: per-anchor score = sigmoid(max logit), float4 ---------------------
__global__ __launch_bounds__(256) void k_scores(
    const float* __restrict__ c0, const float* __restrict__ c1,
    const float* __restrict__ c2, const float* __restrict__ c3,
    const float* __restrict__ c4,
    float* __restrict__ scores, unsigned int* __restrict__ hist)
{
    __shared__ unsigned int lh[NBIN / 2];          // 64 KB, 16-bit packed counts
    const int b = blockIdx.y;
    for (int i = threadIdx.x; i < NBIN / 2; i += 256) lh[i] = 0u;
    __syncthreads();

    #pragma unroll
    for (int r = 0; r < 2; ++r) {
        int f4 = blockIdx.x * 512 + r * 256 + threadIdx.x;
        if (f4 < NANCH / 4) {
            int i = f4 * 4;
            int lvl, h, s, pos;
            levelOf(i, lvl, h, s, pos);
            int hh = h * h;
            const float* cp = (lvl == 0) ? c0 : (lvl == 1) ? c1 : (lvl == 2) ? c2
                              : (lvl == 3) ? c3 : c4;
            const float* base = cp + (size_t)b * NCLS * hh + pos;
            float4 mx = make_float4(-1e30f, -1e30f, -1e30f, -1e30f);
            #pragma unroll
            for (int c = 0; c < NCLS; ++c) {
                float4 v = *(const float4*)(base + (size_t)c * hh);
                mx.x = fmaxf(mx.x, v.x); mx.y = fmaxf(mx.y, v.y);
                mx.z = fmaxf(mx.z, v.z); mx.w = fmaxf(mx.w, v.w);
            }
            float4 sc = make_float4(sigmoidf(mx.x), sigmoidf(mx.y),
                                    sigmoidf(mx.z), sigmoidf(mx.w));
            *(float4*)(scores + (size_t)b * NANCH + i) = sc;
            unsigned int bin;
            bin = __float_as_uint(sc.x) >> BSHIFT;
            atomicAdd(&lh[bin >> 1], 1u << ((bin & 1) << 4));
            bin = __float_as_uint(sc.y) >> BSHIFT;
            atomicAdd(&lh[bin >> 1], 1u << ((bin & 1) << 4));
            bin = __float_as_uint(sc.z) >> BSHIFT;
            atomicAdd(&lh[bin >> 1], 1u << ((bin & 1) << 4));
            bin = __float_as_uint(sc.w) >> BSHIFT;
            atomicAdd(&lh[bin >> 1], 1u << ((bin & 1) << 4));
        }
    }
    __syncthreads();

    unsigned int* hb = hist + (size_t)b * NBIN;
    for (int wd = threadIdx.x; wd < NBIN / 2; wd += 256) {
        unsigned int v = lh[wd];
        if (v) {
            unsigned int lo = v & 0xFFFFu, hi = v >> 16;
            if (lo) atomicAdd(&hb[wd * 2], lo);
            if (hi) atomicAdd(&hb[wd * 2 + 1], hi);
        }
    }
}

// ---- Kernel 2a: find threshold bin per batch (K-th largest), parallel scan ------
__global__ __launch_bounds__(256) void k_findT(
    const unsigned int* __restrict__ hist, int* __restrict__ tbin)
{
    int b = blockIdx.x;
    int tid = threadIdx.x;
    const unsigned int* hb = hist + (size_t)b * NBIN;
    __shared__ unsigned int sc[256];
    __shared__ unsigned int fsc[128];
    __shared__ int s_c, s_t;

    unsigned int s = 0;
    const uint4* hv = (const uint4*)(hb + (size_t)tid * 128);
    #pragma unroll 8
    for (int k = 0; k < 32; ++k) {
        uint4 v = hv[k];
        s += v.x + v.y + v.z + v.w;
    }
    sc[tid] = s;
    if (tid == 0) { s_c = 0; s_t = 0; }
    __syncthreads();
    for (int d = 1; d < 256; d <<= 1) {
        unsigned int add = (tid + d < 256) ? sc[tid + d] : 0;
        __syncthreads();
        sc[tid] += add;
        __syncthreads();
    }
    if (sc[tid] >= (unsigned int)KTOP && (tid == 255 || sc[tid + 1] < (unsigned int)KTOP))
        s_c = tid;
    __syncthreads();
    int c = s_c;
    unsigned int hi = (c < 255) ? sc[c + 1] : 0;
    if (tid < 128) fsc[tid] = hb[c * 128 + tid];
    __syncthreads();
    for (int d = 1; d < 128; d <<= 1) {
        unsigned int add = (tid < 128 && tid + d < 128) ? fsc[tid + d] : 0;
        __syncthreads();
        if (tid < 128) fsc[tid] += add;
        __syncthreads();
    }
    if (tid < 128 && hi + fsc[tid] >= (unsigned int)KTOP &&
        (tid == 127 || hi + fsc[tid + 1] < (unsigned int)KTOP))
        s_t = tid;
    __syncthreads();
    if (tid == 0) tbin[b] = c * 128 + s_t;
}

// ---- Kernel 2b: compact candidates — block-aggregated, padded counters ----------
__global__ __launch_bounds__(256) void k_compact(
    const float* __restrict__ scores, const int* __restrict__ tbin,
    int* __restrict__ cnt, unsigned long long* __restrict__ cand)
{
    const int b = blockIdx.y;
    const int t4 = blockIdx.x * 256 + threadIdx.x;   // float4 index within batch
    __shared__ int lcnt;
    __shared__ int lbase;
    if (threadIdx.x == 0) lcnt = 0;
    __syncthreads();

    const int T = tbin[b];
    const bool in = (t4 < NANCH / 4);
    float4 v = make_float4(0.f, 0.f, 0.f, 0.f);
    if (in) v = *(const float4*)(scores + (size_t)b * NANCH + 4 * (size_t)t4);
    unsigned int bits[4] = { __float_as_uint(v.x), __float_as_uint(v.y),
                             __float_as_uint(v.z), __float_as_uint(v.w) };
    int rank[4];
    #pragma unroll
    for (int k = 0; k < 4; ++k) {
        bool pass = in && ((int)(bits[k] >> BSHIFT) >= T);
        rank[k] = pass ? atomicAdd(&lcnt, 1) : -1;
    }
    __syncthreads();
    if (threadIdx.x == 0) lbase = atomicAdd(&cnt[b * 16], lcnt);
    __syncthreads();
    const int base = lbase;
    #pragma unroll
    for (int k = 0; k < 4; ++k) {
        if (rank[k] >= 0) {
            int p = base + rank[k];
            if (p < CAND) {
                unsigned int idx = 4u * (unsigned int)t4 + (unsigned int)k;
                cand[(size_t)b * CAND + p] =
                    ((unsigned long long)bits[k] << 32) |
                    (unsigned long long)(0xFFFFFFFFu - idx);
            }
        }
    }
}

// ---- Kernel 2c: per-batch bitonic sort of candidates, emit exact top-K ----------
__global__ __launch_bounds__(1024) void k_sortk(
    const unsigned long long* __restrict__ cand, const int* __restrict__ cnt,
    float* __restrict__ tsc, int* __restrict__ tix)
{
    int b = blockIdx.x;
    int tid = threadIdx.x;
    __shared__ unsigned long long keys[CAND];
    int n = cnt[b * 16]; if (n > CAND) n = CAND;
    for (int i = tid; i < CAND; i += 1024)
        keys[i] = (i < n) ? cand[(size_t)b * CAND + i] : 0ull;
    __syncthreads();
    for (int sz = 2; sz <= CAND; sz <<= 1) {
        for (int st = sz >> 1; st > 0; st >>= 1) {
            for (int i = tid; i < CAND; i += 1024) {
                int j = i ^ st;
                if (j > i) {
                    unsigned long long a = keys[i], c = keys[j];
                    bool desc = ((i & sz) == 0);
                    if (desc ? (a < c) : (a > c)) { keys[i] = c; keys[j] = a; }
                }
            }
            __syncthreads();
        }
    }
    if (tid < KTOP) {
        unsigned long long key = keys[tid];
        tsc[b * KTOP + tid] = __uint_as_float((unsigned int)(key >> 32));
        tix[b * KTOP + tid] = (int)(0xFFFFFFFFu - (unsigned int)(key & 0xFFFFFFFFull));
    }
}

// ---- Kernel 3: decode boxes + exact class argmax for selected anchors -----------
__global__ __launch_bounds__(256) void k_decode(
    const float* __restrict__ c0, const float* __restrict__ c1,
    const float* __restrict__ c2, const float* __restrict__ c3,
    const float* __restrict__ c4,
    const float* __restrict__ r0, const float* __restrict__ r1,
    const float* __restrict__ r2, const float* __restrict__ r3,
    const float* __restrict__ r4,
    const float* __restrict__ t0, const float* __restrict__ t1,
    const float* __restrict__ t2, const float* __restrict__ t3,
    const float* __restrict__ t4,
    const float* __restrict__ q0, const float* __restrict__ q1,
    const float* __restrict__ q2, const float* __restrict__ q3,
    const float* __restrict__ q4,
    const int* __restrict__ tix, float* __restrict__ boxes, int* __restrict__ clstop)
{
    int g = blockIdx.x * 256 + threadIdx.x;
    if (g >= BATCH * KTOP) return;
    int b = g / KTOP;
    int idx = tix[g];
    int lvl, h, s, pos;
    levelOf(idx, lvl, h, s, pos);
    int y = pos / h, x = pos - y * h;
    int hh = h * h;
    const float* cp = (lvl == 0) ? c0 : (lvl == 1) ? c1 : (lvl == 2) ? c2 : (lvl == 3) ? c3 : c4;
    const float* rp = (lvl == 0) ? r0 : (lvl == 1) ? r1 : (lvl == 2) ? r2 : (lvl == 3) ? r3 : r4;
    const float* tp = (lvl == 0) ? t0 : (lvl == 1) ? t1 : (lvl == 2) ? t2 : (lvl == 3) ? t3 : t4;
    const float* qp = (lvl == 0) ? q0 : (lvl == 1) ? q1 : (lvl == 2) ? q2 : (lvl == 3) ? q3 : q4;
    int off = y * h + x;

    const float* cb = cp + (size_t)b * NCLS * hh + off;
    float bestc = -1e30f; int bc = 0;
    #pragma unroll
    for (int c = 0; c < NCLS; ++c) {
        float v = sigmoidf(cb[(size_t)c * hh]);
        if (v > bestc) { bestc = v; bc = c; }
    }
    clstop[g] = bc + 1;

    const float* tb = tp + (size_t)b * NTH * hh + off;
    float best = -1e30f; int bt = 0;
    #pragma unroll
    for (int c = 0; c < NTH; ++c) {
        float v = sigmoidf(tb[(size_t)c * hh]);
        if (v > best) { best = v; bt = c; }
    }
    float theta = (float)(bt + 1) * 10.0f + qp[(size_t)b * hh + off];

    const float* rb = rp + (size_t)b * 5 * hh + off;
    float fs = (float)s;
    float rr0 = rb[0] * fs;
    float rr1 = rb[(size_t)hh] * fs;
    float rr2 = rb[(size_t)2 * hh] * fs;
    float rr3 = rb[(size_t)3 * hh] * fs;
    float cx = (float)(x * s + (s >> 1));
    float cy = (float)(y * s + (s >> 1));
    float* op = boxes + (size_t)g * 5;
    op[0] = cx - rr0;
    op[1] = cy - rr1;
    op[2] = cx + rr2;
    op[3] = cy + rr3;
    op[4] = theta;
}

// ---- Kernel 4a: suppression bitmask, ROW-major [b][1024][16] ---------------------
__global__ __launch_bounds__(256) void k_mask(
    const float* __restrict__ boxes, unsigned long long* __restrict__ mask)
{
    int b = blockIdx.x;
    __shared__ float bx1[KTOP], by1[KTOP], bx2[KTOP], by2[KTOP], bar[KTOP];
    for (int r = threadIdx.x; r < KTOP; r += 256) {
        const float* p = boxes + ((size_t)(b * KTOP + r)) * 5;
        float x1 = p[0], y1 = p[1], x2 = p[2], y2 = p[3];
        bx1[r] = x1; by1[r] = y1; bx2[r] = x2; by2[r] = y2;
        bar[r] = fmaxf(x2 - x1, 0.0f) * fmaxf(y2 - y1, 0.0f);
    }
    __syncthreads();
    int i = (blockIdx.y << 4) + (threadIdx.x >> 4);
    int w = threadIdx.x & 15;
    int j0 = w << 6;
    int lo = (j0 > i + 1) ? j0 : (i + 1);
    int hi = (j0 + 64 < KTOP) ? (j0 + 64) : KTOP;
    unsigned long long m = 0ull;
    if (i < KTOP && lo < hi) {
        float x1 = bx1[i], y1 = by1[i], x2 = bx2[i], y2 = by2[i], ai = bar[i];
        for (int j = lo; j < hi; ++j) {
            float iw = fminf(x2, bx2[j]) - fmaxf(x1, bx1[j]);
            iw = fmaxf(iw, 0.0f);
            float ih = fminf(y2, by2[j]) - fmaxf(y1, by1[j]);
            ih = fmaxf(ih, 0.0f);
            float inter = iw * ih;
            float u = ai + bar[j] - inter;
            float iou = inter / fmaxf(u, 1e-8f);
            if (iou > 0.3f) m |= (1ull << (j - j0));
        }
    }
    mask[(((size_t)b * 1024 + i) << 4) + w] = m;
}

// ---- Kernel 4b: greedy NMS — sparse exact chain, prefetched rows, one wave ------
// Exploits exact sparsity: a kept box with an all-zero in-word row cannot change
// remw, so all pending zero-row boxes before the next nonzero-row pending box are
// kept in ONE step. Iterations/word = #kept boxes with nonzero rows (typ. 0-5,
// worst-case 64 = still exact). Cross-word suppression via sparse LDS atomicOr.
#define LOADROW(R, W) do {                                                          \
    const ulonglong2* rp2 = (const ulonglong2*)(mask +                              \
        (((size_t)b * 1024 + ((W) << 6) + l) << 4));                                \
    _Pragma("unroll")                                                               \
    for (int p = 0; p < 8; ++p) {                                                   \
        ulonglong2 v = rp2[p]; R[2 * p] = v.x; R[2 * p + 1] = v.y;                  \
    }                                                                               \
} while (0)

#define PROC(W, R) do {                                                             \
    const unsigned long long rowword = R[W];                                        \
    unsigned long long zr = __ballot(rowword == 0ull);                              \
    unsigned long long remw = sremv[W];                                             \
    unsigned long long pend = vw[W] & ~remw;                                        \
    unsigned long long keptm = 0ull;                                                \
    while (pend) {                                                                  \
        unsigned long long nzp = pend & ~zr;                                        \
        if (!nzp) { keptm |= pend; break; }                                         \
        int jj = __builtin_ctzll(nzp);                                              \
        unsigned long long low = (1ull << jj); low = (low << 1) - 1ull;             \
        keptm |= pend & low;                                                        \
        remw |= shfl_u64(rowword, jj);                                              \
        pend &= ~low; pend &= ~remw;                                                \
    }                                                                               \
    if (l == 0) skeep[W] = keptm;                                                   \
    if ((keptm >> l) & 1ull) {                                                      \
        _Pragma("unroll")                                                           \
        for (int w2 = (W) + 1; w2 < NWORDS; ++w2)                                   \
            if (R[w2]) atomicOr64Shared(&sremv[w2], R[w2]);                         \
    }                                                                               \
} while (0)

__global__ __launch_bounds__(64) void k_nms(
    const unsigned long long* __restrict__ mask,   // [b][1024][16]
    const float* __restrict__ tsc, const int* __restrict__ clstop,
    const float* __restrict__ boxes, float* __restrict__ out)
{
    const int b = blockIdx.x;
    const int l = threadIdx.x;
    __shared__ unsigned long long sremv[NWORDS];
    __shared__ unsigned long long skeep[NWORDS];

    if (l < NWORDS) sremv[l] = 0ull;   // single wave: in-order LDS, no barrier

    unsigned long long vw[NWORDS];
    #pragma unroll
    for (int w = 0; w < NWORDS; ++w) {
        int i = (w << 6) + l;
        bool v = (i < KTOP) && (tsc[b * KTOP + i] >= 0.05f);
        vw[w] = __ballot(v);
    }

    unsigned long long rowA[NWORDS], rowB[NWORDS];
    LOADROW(rowA, 0);
    LOADROW(rowB, 1);   PROC(0, rowA);
    LOADROW(rowA, 2);   PROC(1, rowB);
    LOADROW(rowB, 3);   PROC(2, rowA);
    LOADROW(rowA, 4);   PROC(3, rowB);
    LOADROW(rowB, 5);   PROC(4, rowA);
    LOADROW(rowA, 6);   PROC(5, rowB);
    LOADROW(rowB, 7);   PROC(6, rowA);
    LOADROW(rowA, 8);   PROC(7, rowB);
    LOADROW(rowB, 9);   PROC(8, rowA);
    LOADROW(rowA, 10);  PROC(9, rowB);
    LOADROW(rowB, 11);  PROC(10, rowA);
    LOADROW(rowA, 12);  PROC(11, rowB);
    LOADROW(rowB, 13);  PROC(12, rowA);
    LOADROW(rowA, 14);  PROC(13, rowB);
    LOADROW(rowB, 15);  PROC(14, rowA);
    PROC(15, rowB);

    // fused masked output write
    #pragma unroll
    for (int w = 0; w < NWORDS; ++w) {
        int i = (w << 6) + l;
        if (i < KTOP) {
            int g = b * KTOP + i;
            float fk = (float)((skeep[w] >> l) & 1ull);
            out[g] = tsc[g] * fk;
            out[BATCH * KTOP + g] = (float)clstop[g] * fk;
            const float* bp = boxes + (size_t)g * 5;
            float* op = out + 2 * BATCH * KTOP + (size_t)g * 5;
            op[0] = bp[0] * fk;
            op[1] = bp[1] * fk;
            op[2] = bp[2] * fk;
            op[3] = bp[3] * fk;
            op[4] = bp[4] * fk;
        }
    }
}

extern "C" void kernel_launch(void* const* d_in, const int* in_sizes, int n_in,
                              void* d_out, int out_size, void* d_ws, size_t ws_size,
                              hipStream_t stream) {
    const float* c0 = (const float*)d_in[0];
    const float* c1 = (const float*)d_in[1];
    const float* c2 = (const float*)d_in[2];
    const float* c3 = (const float*)d_in[3];
    const float* c4 = (const float*)d_in[4];
    const float* r0 = (const float*)d_in[5];
    const float* r1 = (const float*)d_in[6];
    const float* r2 = (const float*)d_in[7];
    const float* r3 = (const float*)d_in[8];
    const float* r4 = (const float*)d_in[9];
    const float* t0 = (const float*)d_in[10];
    const float* t1 = (const float*)d_in[11];
    const float* t2 = (const float*)d_in[12];
    const float* t3 = (const float*)d_in[13];
    const float* t4 = (const float*)d_in[14];
    const float* q0 = (const float*)d_in[15];
    const float* q1 = (const float*)d_in[16];
    const float* q2 = (const float*)d_in[17];
    const float* q3 = (const float*)d_in[18];
    const float* q4 = (const float*)d_in[19];

    // Workspace layout, total 5,753,920 B. Aliases safe by stream order:
    //   hist (k_scores→k_findT) aliases mask (k_mask→k_nms)   [findT before mask]
    //   cand (k_compact→k_sortk) aliases boxes (k_decode→...) [sortk before decode]
    char* ws = (char*)d_ws;
    float*              scores  = (float*)(ws + 0);          // 3,142,656
    float*              tsc     = (float*)(ws + 3142656);    //    64,000
    int*                tix     = (int*)(ws + 3206656);      //    64,000
    float*              boxes   = (float*)(ws + 3270656);    //   320,000
    unsigned long long* cand    = (unsigned long long*)(ws + 3270656); // 262,144 alias
    int*                clstop  = (int*)(ws + 3590656);      //    64,000
    unsigned long long* mask    = (unsigned long long*)(ws + 3654656); // 2,097,152
    unsigned int*       hist    = (unsigned int*)(ws + 3654656);       // alias
    int*                tcnt    = (int*)(ws + 5751808);      //     1,024 (16 x 64B)
    int*                tbin    = (int*)(ws + 5752832);      //        64
    float*              out     = (float*)d_out;

    // zero hist + tcnt (contiguous: 2,097,152 + 1,024)
    hipMemsetAsync(ws + 3654656, 0, 2098176, stream);

    k_scores<<<dim3(24, BATCH), 256, 0, stream>>>(
        c0, c1, c2, c3, c4, scores, hist);
    k_findT<<<BATCH, 256, 0, stream>>>(hist, tbin);
    k_compact<<<dim3(48, BATCH), 256, 0, stream>>>(scores, tbin, tcnt, cand);
    k_sortk<<<BATCH, 1024, 0, stream>>>(cand, tcnt, tsc, tix);
    k_decode<<<(BATCH * KTOP + 255) / 256, 256, 0, stream>>>(
        c0, c1, c2, c3, c4,
        r0, r1, r2, r3, r4, t0, t1, t2, t3, t4, q0, q1, q2, q3, q4,
        tix, boxes, clstop);
    k_mask<<<dim3(BATCH, 64), 256, 0, stream>>>(boxes, mask);
    k_nms<<<BATCH, 64, 0, stream>>>(mask, tsc, clstop, boxes, out);
}

// Round 10
// 123.267 us; speedup vs baseline: 1.4592x; 1.1772x over previous
//
#include <hip/hip_runtime.h>
#include <stdint.h>

#define NCLS   15
#define NTH    18
#define BATCH  16
#define NANCH  49104
#define KTOP   1000
#define NWORDS 16   // 16*64 = 1024 >= 1000
#define NBIN   32768
#define BSHIFT 15
#define CAND   2048

__device__ __forceinline__ float sigmoidf(float x) {
    return 1.0f / (1.0f + expf(-x));
}

__device__ __forceinline__ void levelOf(int i, int& lvl, int& h, int& s, int& pos) {
    if (i < 36864)      { lvl = 0; h = 192; s = 8;   pos = i; }
    else if (i < 46080) { lvl = 1; h = 96;  s = 16;  pos = i - 36864; }
    else if (i < 48384) { lvl = 2; h = 48;  s = 32;  pos = i - 46080; }
    else if (i < 48960) { lvl = 3; h = 24;  s = 64;  pos = i - 48384; }
    else                { lvl = 4; h = 12;  s = 128; pos = i - 48960; }
}

__device__ __forceinline__ unsigned long long shfl_u64(unsigned long long v, int src) {
    int lo = __shfl((int)(unsigned int)(v & 0xFFFFFFFFull), src);
    int hi = __shfl((int)(unsigned int)(v >> 32), src);
    return ((unsigned long long)(unsigned int)hi << 32) | (unsigned long long)(unsigned int)lo;
}

__device__ __forceinline__ void atomicOr64Shared(unsigned long long* p, unsigned long long v) {
    unsigned int* q = (unsigned int*)p;
    unsigned int lo = (unsigned int)v;
    unsigned int hi = (unsigned int)(v >> 32);
    if (lo) atomicOr(q, lo);
    if (hi) atomicOr(q + 1, hi);
}

// ---- Kernel 1: per-anchor score = sigmoid(max logit), float4 ---------------------
__global__ __launch_bounds__(256) void k_scores(
    const float* __restrict__ c0, const float* __restrict__ c1,
    const float* __restrict__ c2, const float* __restrict__ c3,
    const float* __restrict__ c4,
    float* __restrict__ scores, unsigned int* __restrict__ hist)
{
    __shared__ unsigned int lh[NBIN / 2];          // 64 KB, 16-bit packed counts
    const int b = blockIdx.y;
    for (int i = threadIdx.x; i < NBIN / 2; i += 256) lh[i] = 0u;
    __syncthreads();

    #pragma unroll
    for (int r = 0; r < 2; ++r) {
        int f4 = blockIdx.x * 512 + r * 256 + threadIdx.x;
        if (f4 < NANCH / 4) {
            int i = f4 * 4;
            int lvl, h, s, pos;
            levelOf(i, lvl, h, s, pos);
            int hh = h * h;
            const float* cp = (lvl == 0) ? c0 : (lvl == 1) ? c1 : (lvl == 2) ? c2
                              : (lvl == 3) ? c3 : c4;
            const float* base = cp + (size_t)b * NCLS * hh + pos;
            float4 mx = make_float4(-1e30f, -1e30f, -1e30f, -1e30f);
            #pragma unroll
            for (int c = 0; c < NCLS; ++c) {
                float4 v = *(const float4*)(base + (size_t)c * hh);
                mx.x = fmaxf(mx.x, v.x); mx.y = fmaxf(mx.y, v.y);
                mx.z = fmaxf(mx.z, v.z); mx.w = fmaxf(mx.w, v.w);
            }
            float4 sc = make_float4(sigmoidf(mx.x), sigmoidf(mx.y),
                                    sigmoidf(mx.z), sigmoidf(mx.w));
            *(float4*)(scores + (size_t)b * NANCH + i) = sc;
            unsigned int bin;
            bin = __float_as_uint(sc.x) >> BSHIFT;
            atomicAdd(&lh[bin >> 1], 1u << ((bin & 1) << 4));
            bin = __float_as_uint(sc.y) >> BSHIFT;
            atomicAdd(&lh[bin >> 1], 1u << ((bin & 1) << 4));
            bin = __float_as_uint(sc.z) >> BSHIFT;
            atomicAdd(&lh[bin >> 1], 1u << ((bin & 1) << 4));
            bin = __float_as_uint(sc.w) >> BSHIFT;
            atomicAdd(&lh[bin >> 1], 1u << ((bin & 1) << 4));
        }
    }
    __syncthreads();

    unsigned int* hb = hist + (size_t)b * NBIN;
    for (int wd = threadIdx.x; wd < NBIN / 2; wd += 256) {
        unsigned int v = lh[wd];
        if (v) {
            unsigned int lo = v & 0xFFFFu, hi = v >> 16;
            if (lo) atomicAdd(&hb[wd * 2], lo);
            if (hi) atomicAdd(&hb[wd * 2 + 1], hi);
        }
    }
}

// ---- Kernel 2a: find threshold bin per batch (K-th largest), parallel scan ------
__global__ __launch_bounds__(256) void k_findT(
    const unsigned int* __restrict__ hist, int* __restrict__ tbin)
{
    int b = blockIdx.x;
    int tid = threadIdx.x;
    const unsigned int* hb = hist + (size_t)b * NBIN;
    __shared__ unsigned int sc[256];
    __shared__ unsigned int fsc[128];
    __shared__ int s_c, s_t;

    unsigned int s = 0;
    const uint4* hv = (const uint4*)(hb + (size_t)tid * 128);
    #pragma unroll 8
    for (int k = 0; k < 32; ++k) {
        uint4 v = hv[k];
        s += v.x + v.y + v.z + v.w;
    }
    sc[tid] = s;
    if (tid == 0) { s_c = 0; s_t = 0; }
    __syncthreads();
    for (int d = 1; d < 256; d <<= 1) {
        unsigned int add = (tid + d < 256) ? sc[tid + d] : 0;
        __syncthreads();
        sc[tid] += add;
        __syncthreads();
    }
    if (sc[tid] >= (unsigned int)KTOP && (tid == 255 || sc[tid + 1] < (unsigned int)KTOP))
        s_c = tid;
    __syncthreads();
    int c = s_c;
    unsigned int hi = (c < 255) ? sc[c + 1] : 0;
    if (tid < 128) fsc[tid] = hb[c * 128 + tid];
    __syncthreads();
    for (int d = 1; d < 128; d <<= 1) {
        unsigned int add = (tid < 128 && tid + d < 128) ? fsc[tid + d] : 0;
        __syncthreads();
        if (tid < 128) fsc[tid] += add;
        __syncthreads();
    }
    if (tid < 128 && hi + fsc[tid] >= (unsigned int)KTOP &&
        (tid == 127 || hi + fsc[tid + 1] < (unsigned int)KTOP))
        s_t = tid;
    __syncthreads();
    if (tid == 0) tbin[b] = c * 128 + s_t;
}

// ---- Kernel 2b: compact candidates — block-aggregated, padded counters ----------
__global__ __launch_bounds__(256) void k_compact(
    const float* __restrict__ scores, const int* __restrict__ tbin,
    int* __restrict__ cnt, unsigned long long* __restrict__ cand)
{
    const int b = blockIdx.y;
    const int t4 = blockIdx.x * 256 + threadIdx.x;   // float4 index within batch
    __shared__ int lcnt;
    __shared__ int lbase;
    if (threadIdx.x == 0) lcnt = 0;
    __syncthreads();

    const int T = tbin[b];
    const bool in = (t4 < NANCH / 4);
    float4 v = make_float4(0.f, 0.f, 0.f, 0.f);
    if (in) v = *(const float4*)(scores + (size_t)b * NANCH + 4 * (size_t)t4);
    unsigned int bits[4] = { __float_as_uint(v.x), __float_as_uint(v.y),
                             __float_as_uint(v.z), __float_as_uint(v.w) };
    int rank[4];
    #pragma unroll
    for (int k = 0; k < 4; ++k) {
        bool pass = in && ((int)(bits[k] >> BSHIFT) >= T);
        rank[k] = pass ? atomicAdd(&lcnt, 1) : -1;
    }
    __syncthreads();
    if (threadIdx.x == 0) lbase = atomicAdd(&cnt[b * 16], lcnt);
    __syncthreads();
    const int base = lbase;
    #pragma unroll
    for (int k = 0; k < 4; ++k) {
        if (rank[k] >= 0) {
            int p = base + rank[k];
            if (p < CAND) {
                unsigned int idx = 4u * (unsigned int)t4 + (unsigned int)k;
                cand[(size_t)b * CAND + p] =
                    ((unsigned long long)bits[k] << 32) |
                    (unsigned long long)(0xFFFFFFFFu - idx);
            }
        }
    }
}

// ---- Kernel 2c: per-batch bitonic sort of candidates, emit exact top-K ----------
__global__ __launch_bounds__(1024) void k_sortk(
    const unsigned long long* __restrict__ cand, const int* __restrict__ cnt,
    float* __restrict__ tsc, int* __restrict__ tix)
{
    int b = blockIdx.x;
    int tid = threadIdx.x;
    __shared__ unsigned long long keys[CAND];
    int n = cnt[b * 16]; if (n > CAND) n = CAND;
    for (int i = tid; i < CAND; i += 1024)
        keys[i] = (i < n) ? cand[(size_t)b * CAND + i] : 0ull;
    __syncthreads();
    for (int sz = 2; sz <= CAND; sz <<= 1) {
        for (int st = sz >> 1; st > 0; st >>= 1) {
            for (int i = tid; i < CAND; i += 1024) {
                int j = i ^ st;
                if (j > i) {
                    unsigned long long a = keys[i], c = keys[j];
                    bool desc = ((i & sz) == 0);
                    if (desc ? (a < c) : (a > c)) { keys[i] = c; keys[j] = a; }
                }
            }
            __syncthreads();
        }
    }
    if (tid < KTOP) {
        unsigned long long key = keys[tid];
        tsc[b * KTOP + tid] = __uint_as_float((unsigned int)(key >> 32));
        tix[b * KTOP + tid] = (int)(0xFFFFFFFFu - (unsigned int)(key & 0xFFFFFFFFull));
    }
}

// ---- Kernel 3: decode boxes + exact class argmax for selected anchors -----------
__global__ __launch_bounds__(256) void k_decode(
    const float* __restrict__ c0, const float* __restrict__ c1,
    const float* __restrict__ c2, const float* __restrict__ c3,
    const float* __restrict__ c4,
    const float* __restrict__ r0, const float* __restrict__ r1,
    const float* __restrict__ r2, const float* __restrict__ r3,
    const float* __restrict__ r4,
    const float* __restrict__ t0, const float* __restrict__ t1,
    const float* __restrict__ t2, const float* __restrict__ t3,
    const float* __restrict__ t4,
    const float* __restrict__ q0, const float* __restrict__ q1,
    const float* __restrict__ q2, const float* __restrict__ q3,
    const float* __restrict__ q4,
    const int* __restrict__ tix, float* __restrict__ boxes, int* __restrict__ clstop)
{
    int g = blockIdx.x * 256 + threadIdx.x;
    if (g >= BATCH * KTOP) return;
    int b = g / KTOP;
    int idx = tix[g];
    int lvl, h, s, pos;
    levelOf(idx, lvl, h, s, pos);
    int y = pos / h, x = pos - y * h;
    int hh = h * h;
    const float* cp = (lvl == 0) ? c0 : (lvl == 1) ? c1 : (lvl == 2) ? c2 : (lvl == 3) ? c3 : c4;
    const float* rp = (lvl == 0) ? r0 : (lvl == 1) ? r1 : (lvl == 2) ? r2 : (lvl == 3) ? r3 : r4;
    const float* tp = (lvl == 0) ? t0 : (lvl == 1) ? t1 : (lvl == 2) ? t2 : (lvl == 3) ? t3 : t4;
    const float* qp = (lvl == 0) ? q0 : (lvl == 1) ? q1 : (lvl == 2) ? q2 : (lvl == 3) ? q3 : q4;
    int off = y * h + x;

    const float* cb = cp + (size_t)b * NCLS * hh + off;
    float bestc = -1e30f; int bc = 0;
    #pragma unroll
    for (int c = 0; c < NCLS; ++c) {
        float v = sigmoidf(cb[(size_t)c * hh]);
        if (v > bestc) { bestc = v; bc = c; }
    }
    clstop[g] = bc + 1;

    const float* tb = tp + (size_t)b * NTH * hh + off;
    float best = -1e30f; int bt = 0;
    #pragma unroll
    for (int c = 0; c < NTH; ++c) {
        float v = sigmoidf(tb[(size_t)c * hh]);
        if (v > best) { best = v; bt = c; }
    }
    float theta = (float)(bt + 1) * 10.0f + qp[(size_t)b * hh + off];

    const float* rb = rp + (size_t)b * 5 * hh + off;
    float fs = (float)s;
    float rr0 = rb[0] * fs;
    float rr1 = rb[(size_t)hh] * fs;
    float rr2 = rb[(size_t)2 * hh] * fs;
    float rr3 = rb[(size_t)3 * hh] * fs;
    float cx = (float)(x * s + (s >> 1));
    float cy = (float)(y * s + (s >> 1));
    float* op = boxes + (size_t)g * 5;
    op[0] = cx - rr0;
    op[1] = cy - rr1;
    op[2] = cx + rr2;
    op[3] = cy + rr3;
    op[4] = theta;
}

// ---- Kernel 4a: suppression bitmask — wave-uniform j-loop, broadcast LDS --------
// grid (BATCH, 16). Lane l owns row i = 64*by + l; wave wv computes words
// w = by+wv, by+wv+4, ... (upper triangle only — k_nms never reads w < row/64).
// Inner j-loop is wave-uniform: all 64 lanes read bx*[j] at the SAME address
// (LDS broadcast, zero bank conflicts). Out-of-range rows/cols staged as zero
// boxes -> IoU==0 exactly -> bit 0, matching the reference.
__global__ __launch_bounds__(256) void k_mask(
    const float* __restrict__ boxes, unsigned long long* __restrict__ mask)
{
    const int b = blockIdx.x;
    const int by = blockIdx.y;
    __shared__ float bx1[1024], by1[1024], bx2[1024], by2[1024], bar[1024];
    for (int r = threadIdx.x; r < 1024; r += 256) {
        float x1 = 0.f, y1 = 0.f, x2 = 0.f, y2 = 0.f;
        if (r < KTOP) {
            const float* p = boxes + ((size_t)(b * KTOP + r)) * 5;
            x1 = p[0]; y1 = p[1]; x2 = p[2]; y2 = p[3];
        }
        bx1[r] = x1; by1[r] = y1; bx2[r] = x2; by2[r] = y2;
        bar[r] = fmaxf(x2 - x1, 0.0f) * fmaxf(y2 - y1, 0.0f);
    }
    __syncthreads();

    const int l  = threadIdx.x & 63;
    const int wv = threadIdx.x >> 6;
    const int i  = (by << 6) + l;
    const float x1 = bx1[i], y1 = by1[i], x2 = bx2[i], y2 = by2[i], ai = bar[i];

    for (int w = by + wv; w < NWORDS; w += 4) {
        const int j0 = w << 6;
        unsigned long long m = 0ull;
        #pragma unroll 8
        for (int jj = 0; jj < 64; ++jj) {
            const int j = j0 + jj;
            float iw = fminf(x2, bx2[j]) - fmaxf(x1, bx1[j]);
            iw = fmaxf(iw, 0.0f);
            float ih = fminf(y2, by2[j]) - fmaxf(y1, by1[j]);
            ih = fmaxf(ih, 0.0f);
            float inter = iw * ih;
            float u = ai + bar[j] - inter;
            float iou = inter / fmaxf(u, 1e-8f);
            unsigned long long bit = (iou > 0.3f && j > i) ? 1ull : 0ull;
            m |= bit << jj;
        }
        mask[(((size_t)b * 1024 + i) << 4) + w] = m;
    }
}

// ---- Kernel 4b: greedy NMS — sparse exact chain, prefetched rows, one wave ------
#define LOADROW(R, W) do {                                                          \
    const ulonglong2* rp2 = (const ulonglong2*)(mask +                              \
        (((size_t)b * 1024 + ((W) << 6) + l) << 4));                                \
    _Pragma("unroll")                                                               \
    for (int p = 0; p < 8; ++p) {                                                   \
        ulonglong2 v = rp2[p]; R[2 * p] = v.x; R[2 * p + 1] = v.y;                  \
    }                                                                               \
} while (0)

#define PROC(W, R) do {                                                             \
    const unsigned long long rowword = R[W];                                        \
    unsigned long long zr = __ballot(rowword == 0ull);                              \
    unsigned long long remw = sremv[W];                                             \
    unsigned long long pend = vw[W] & ~remw;                                        \
    unsigned long long keptm = 0ull;                                                \
    while (pend) {                                                                  \
        unsigned long long nzp = pend & ~zr;                                        \
        if (!nzp) { keptm |= pend; break; }                                         \
        int jj = __builtin_ctzll(nzp);                                              \
        unsigned long long low = (1ull << jj); low = (low << 1) - 1ull;             \
        keptm |= pend & low;                                                        \
        remw |= shfl_u64(rowword, jj);                                              \
        pend &= ~low; pend &= ~remw;                                                \
    }                                                                               \
    if (l == 0) skeep[W] = keptm;                                                   \
    if ((keptm >> l) & 1ull) {                                                      \
        _Pragma("unroll")                                                           \
        for (int w2 = (W) + 1; w2 < NWORDS; ++w2)                                   \
            if (R[w2]) atomicOr64Shared(&sremv[w2], R[w2]);                         \
    }                                                                               \
} while (0)

__global__ __launch_bounds__(64) void k_nms(
    const unsigned long long* __restrict__ mask,   // [b][1024][16]
    const float* __restrict__ tsc, const int* __restrict__ clstop,
    const float* __restrict__ boxes, float* __restrict__ out)
{
    const int b = blockIdx.x;
    const int l = threadIdx.x;
    __shared__ unsigned long long sremv[NWORDS];
    __shared__ unsigned long long skeep[NWORDS];

    if (l < NWORDS) sremv[l] = 0ull;   // single wave: in-order LDS, no barrier

    unsigned long long vw[NWORDS];
    #pragma unroll
    for (int w = 0; w < NWORDS; ++w) {
        int i = (w << 6) + l;
        bool v = (i < KTOP) && (tsc[b * KTOP + i] >= 0.05f);
        vw[w] = __ballot(v);
    }

    unsigned long long rowA[NWORDS], rowB[NWORDS];
    LOADROW(rowA, 0);
    LOADROW(rowB, 1);   PROC(0, rowA);
    LOADROW(rowA, 2);   PROC(1, rowB);
    LOADROW(rowB, 3);   PROC(2, rowA);
    LOADROW(rowA, 4);   PROC(3, rowB);
    LOADROW(rowB, 5);   PROC(4, rowA);
    LOADROW(rowA, 6);   PROC(5, rowB);
    LOADROW(rowB, 7);   PROC(6, rowA);
    LOADROW(rowA, 8);   PROC(7, rowB);
    LOADROW(rowB, 9);   PROC(8, rowA);
    LOADROW(rowA, 10);  PROC(9, rowB);
    LOADROW(rowB, 11);  PROC(10, rowA);
    LOADROW(rowA, 12);  PROC(11, rowB);
    LOADROW(rowB, 13);  PROC(12, rowA);
    LOADROW(rowA, 14);  PROC(13, rowB);
    LOADROW(rowB, 15);  PROC(14, rowA);
    PROC(15, rowB);

    // fused masked output write
    #pragma unroll
    for (int w = 0; w < NWORDS; ++w) {
        int i = (w << 6) + l;
        if (i < KTOP) {
            int g = b * KTOP + i;
            float fk = (float)((skeep[w] >> l) & 1ull);
            out[g] = tsc[g] * fk;
            out[BATCH * KTOP + g] = (float)clstop[g] * fk;
            const float* bp = boxes + (size_t)g * 5;
            float* op = out + 2 * BATCH * KTOP + (size_t)g * 5;
            op[0] = bp[0] * fk;
            op[1] = bp[1] * fk;
            op[2] = bp[2] * fk;
            op[3] = bp[3] * fk;
            op[4] = bp[4] * fk;
        }
    }
}

extern "C" void kernel_launch(void* const* d_in, const int* in_sizes, int n_in,
                              void* d_out, int out_size, void* d_ws, size_t ws_size,
                              hipStream_t stream) {
    const float* c0 = (const float*)d_in[0];
    const float* c1 = (const float*)d_in[1];
    const float* c2 = (const float*)d_in[2];
    const float* c3 = (const float*)d_in[3];
    const float* c4 = (const float*)d_in[4];
    const float* r0 = (const float*)d_in[5];
    const float* r1 = (const float*)d_in[6];
    const float* r2 = (const float*)d_in[7];
    const float* r3 = (const float*)d_in[8];
    const float* r4 = (const float*)d_in[9];
    const float* t0 = (const float*)d_in[10];
    const float* t1 = (const float*)d_in[11];
    const float* t2 = (const float*)d_in[12];
    const float* t3 = (const float*)d_in[13];
    const float* t4 = (const float*)d_in[14];
    const float* q0 = (const float*)d_in[15];
    const float* q1 = (const float*)d_in[16];
    const float* q2 = (const float*)d_in[17];
    const float* q3 = (const float*)d_in[18];
    const float* q4 = (const float*)d_in[19];

    // Workspace layout, total 5,753,920 B. Aliases safe by stream order:
    //   hist (k_scores→k_findT) aliases mask (k_mask→k_nms)   [findT before mask]
    //   cand (k_compact→k_sortk) aliases boxes (k_decode→...) [sortk before decode]
    char* ws = (char*)d_ws;
    float*              scores  = (float*)(ws + 0);          // 3,142,656
    float*              tsc     = (float*)(ws + 3142656);    //    64,000
    int*                tix     = (int*)(ws + 3206656);      //    64,000
    float*              boxes   = (float*)(ws + 3270656);    //   320,000
    unsigned long long* cand    = (unsigned long long*)(ws + 3270656); // 262,144 alias
    int*                clstop  = (int*)(ws + 3590656);      //    64,000
    unsigned long long* mask    = (unsigned long long*)(ws + 3654656); // 2,097,152
    unsigned int*       hist    = (unsigned int*)(ws + 3654656);       // alias
    int*                tcnt    = (int*)(ws + 5751808);      //     1,024 (16 x 64B)
    int*                tbin    = (int*)(ws + 5752832);      //        64
    float*              out     = (float*)d_out;

    // zero hist + tcnt (contiguous: 2,097,152 + 1,024)
    hipMemsetAsync(ws + 3654656, 0, 2098176, stream);

    k_scores<<<dim3(24, BATCH), 256, 0, stream>>>(
        c0, c1, c2, c3, c4, scores, hist);
    k_findT<<<BATCH, 256, 0, stream>>>(hist, tbin);
    k_compact<<<dim3(48, BATCH), 256, 0, stream>>>(scores, tbin, tcnt, cand);
    k_sortk<<<BATCH, 1024, 0, stream>>>(cand, tcnt, tsc, tix);
    k_decode<<<(BATCH * KTOP + 255) / 256, 256, 0, stream>>>(
        c0, c1, c2, c3, c4,
        r0, r1, r2, r3, r4, t0, t1, t2, t3, t4, q0, q1, q2, q3, q4,
        tix, boxes, clstop);
    k_mask<<<dim3(BATCH, 16), 256, 0, stream>>>(boxes, mask);
    k_nms<<<BATCH, 64, 0, stream>>>(mask, tsc, clstop, boxes, out);
}

// Round 11
// 122.386 us; speedup vs baseline: 1.4697x; 1.0072x over previous
//
#include <hip/hip_runtime.h>
#include <stdint.h>

#define NCLS   15
#define NTH    18
#define BATCH  16
#define NANCH  49104
#define KTOP   1000
#define NWORDS 16   // 16*64 = 1024 >= 1000
#define NBIN   32768
#define BSHIFT 15
#define CAND   2048

__device__ __forceinline__ float sigmoidf(float x) {
    return 1.0f / (1.0f + expf(-x));
}

__device__ __forceinline__ void levelOf(int i, int& lvl, int& h, int& s, int& pos) {
    if (i < 36864)      { lvl = 0; h = 192; s = 8;   pos = i; }
    else if (i < 46080) { lvl = 1; h = 96;  s = 16;  pos = i - 36864; }
    else if (i < 48384) { lvl = 2; h = 48;  s = 32;  pos = i - 46080; }
    else if (i < 48960) { lvl = 3; h = 24;  s = 64;  pos = i - 48384; }
    else                { lvl = 4; h = 12;  s = 128; pos = i - 48960; }
}

__device__ __forceinline__ unsigned long long shfl_u64(unsigned long long v, int src) {
    int lo = __shfl((int)(unsigned int)(v & 0xFFFFFFFFull), src);
    int hi = __shfl((int)(unsigned int)(v >> 32), src);
    return ((unsigned long long)(unsigned int)hi << 32) | (unsigned long long)(unsigned int)lo;
}

__device__ __forceinline__ void atomicOr64Shared(unsigned long long* p, unsigned long long v) {
    unsigned int* q = (unsigned int*)p;
    unsigned int lo = (unsigned int)v;
    unsigned int hi = (unsigned int)(v >> 32);
    if (lo) atomicOr(q, lo);
    if (hi) atomicOr(q + 1, hi);
}

// ---- Kernel 0: zero hist+tcnt (replaces runtime fillBuffer slow path) -----------
__global__ __launch_bounds__(256) void k_zero(uint4* __restrict__ p, int n4)
{
    int i = blockIdx.x * 256 + threadIdx.x;
    if (i < n4) p[i] = make_uint4(0u, 0u, 0u, 0u);
}

// ---- Kernel 1: per-anchor score = sigmoid(max logit), float4 ---------------------
__global__ __launch_bounds__(256) void k_scores(
    const float* __restrict__ c0, const float* __restrict__ c1,
    const float* __restrict__ c2, const float* __restrict__ c3,
    const float* __restrict__ c4,
    float* __restrict__ scores, unsigned int* __restrict__ hist)
{
    __shared__ unsigned int lh[NBIN / 2];          // 64 KB, 16-bit packed counts
    const int b = blockIdx.y;
    for (int i = threadIdx.x; i < NBIN / 2; i += 256) lh[i] = 0u;
    __syncthreads();

    #pragma unroll
    for (int r = 0; r < 2; ++r) {
        int f4 = blockIdx.x * 512 + r * 256 + threadIdx.x;
        if (f4 < NANCH / 4) {
            int i = f4 * 4;
            int lvl, h, s, pos;
            levelOf(i, lvl, h, s, pos);
            int hh = h * h;
            const float* cp = (lvl == 0) ? c0 : (lvl == 1) ? c1 : (lvl == 2) ? c2
                              : (lvl == 3) ? c3 : c4;
            const float* base = cp + (size_t)b * NCLS * hh + pos;
            float4 mx = make_float4(-1e30f, -1e30f, -1e30f, -1e30f);
            #pragma unroll
            for (int c = 0; c < NCLS; ++c) {
                float4 v = *(const float4*)(base + (size_t)c * hh);
                mx.x = fmaxf(mx.x, v.x); mx.y = fmaxf(mx.y, v.y);
                mx.z = fmaxf(mx.z, v.z); mx.w = fmaxf(mx.w, v.w);
            }
            float4 sc = make_float4(sigmoidf(mx.x), sigmoidf(mx.y),
                                    sigmoidf(mx.z), sigmoidf(mx.w));
            *(float4*)(scores + (size_t)b * NANCH + i) = sc;
            unsigned int bin;
            bin = __float_as_uint(sc.x) >> BSHIFT;
            atomicAdd(&lh[bin >> 1], 1u << ((bin & 1) << 4));
            bin = __float_as_uint(sc.y) >> BSHIFT;
            atomicAdd(&lh[bin >> 1], 1u << ((bin & 1) << 4));
            bin = __float_as_uint(sc.z) >> BSHIFT;
            atomicAdd(&lh[bin >> 1], 1u << ((bin & 1) << 4));
            bin = __float_as_uint(sc.w) >> BSHIFT;
            atomicAdd(&lh[bin >> 1], 1u << ((bin & 1) << 4));
        }
    }
    __syncthreads();

    unsigned int* hb = hist + (size_t)b * NBIN;
    for (int wd = threadIdx.x; wd < NBIN / 2; wd += 256) {
        unsigned int v = lh[wd];
        if (v) {
            unsigned int lo = v & 0xFFFFu, hi = v >> 16;
            if (lo) atomicAdd(&hb[wd * 2], lo);
            if (hi) atomicAdd(&hb[wd * 2 + 1], hi);
        }
    }
}

// ---- Kernel 2a: find threshold bin per batch (K-th largest), parallel scan ------
__global__ __launch_bounds__(256) void k_findT(
    const unsigned int* __restrict__ hist, int* __restrict__ tbin)
{
    int b = blockIdx.x;
    int tid = threadIdx.x;
    const unsigned int* hb = hist + (size_t)b * NBIN;
    __shared__ unsigned int sc[256];
    __shared__ unsigned int fsc[128];
    __shared__ int s_c, s_t;

    unsigned int s = 0;
    const uint4* hv = (const uint4*)(hb + (size_t)tid * 128);
    #pragma unroll 8
    for (int k = 0; k < 32; ++k) {
        uint4 v = hv[k];
        s += v.x + v.y + v.z + v.w;
    }
    sc[tid] = s;
    if (tid == 0) { s_c = 0; s_t = 0; }
    __syncthreads();
    for (int d = 1; d < 256; d <<= 1) {
        unsigned int add = (tid + d < 256) ? sc[tid + d] : 0;
        __syncthreads();
        sc[tid] += add;
        __syncthreads();
    }
    if (sc[tid] >= (unsigned int)KTOP && (tid == 255 || sc[tid + 1] < (unsigned int)KTOP))
        s_c = tid;
    __syncthreads();
    int c = s_c;
    unsigned int hi = (c < 255) ? sc[c + 1] : 0;
    if (tid < 128) fsc[tid] = hb[c * 128 + tid];
    __syncthreads();
    for (int d = 1; d < 128; d <<= 1) {
        unsigned int add = (tid < 128 && tid + d < 128) ? fsc[tid + d] : 0;
        __syncthreads();
        if (tid < 128) fsc[tid] += add;
        __syncthreads();
    }
    if (tid < 128 && hi + fsc[tid] >= (unsigned int)KTOP &&
        (tid == 127 || hi + fsc[tid + 1] < (unsigned int)KTOP))
        s_t = tid;
    __syncthreads();
    if (tid == 0) tbin[b] = c * 128 + s_t;
}

// ---- Kernel 2b: compact candidates — block-aggregated, padded counters ----------
__global__ __launch_bounds__(256) void k_compact(
    const float* __restrict__ scores, const int* __restrict__ tbin,
    int* __restrict__ cnt, unsigned long long* __restrict__ cand)
{
    const int b = blockIdx.y;
    const int t4 = blockIdx.x * 256 + threadIdx.x;   // float4 index within batch
    __shared__ int lcnt;
    __shared__ int lbase;
    if (threadIdx.x == 0) lcnt = 0;
    __syncthreads();

    const int T = tbin[b];
    const bool in = (t4 < NANCH / 4);
    float4 v = make_float4(0.f, 0.f, 0.f, 0.f);
    if (in) v = *(const float4*)(scores + (size_t)b * NANCH + 4 * (size_t)t4);
    unsigned int bits[4] = { __float_as_uint(v.x), __float_as_uint(v.y),
                             __float_as_uint(v.z), __float_as_uint(v.w) };
    int rank[4];
    #pragma unroll
    for (int k = 0; k < 4; ++k) {
        bool pass = in && ((int)(bits[k] >> BSHIFT) >= T);
        rank[k] = pass ? atomicAdd(&lcnt, 1) : -1;
    }
    __syncthreads();
    if (threadIdx.x == 0) lbase = atomicAdd(&cnt[b * 16], lcnt);
    __syncthreads();
    const int base = lbase;
    #pragma unroll
    for (int k = 0; k < 4; ++k) {
        if (rank[k] >= 0) {
            int p = base + rank[k];
            if (p < CAND) {
                unsigned int idx = 4u * (unsigned int)t4 + (unsigned int)k;
                cand[(size_t)b * CAND + p] =
                    ((unsigned long long)bits[k] << 32) |
                    (unsigned long long)(0xFFFFFFFFu - idx);
            }
        }
    }
}

// ---- Kernel 2c: per-batch bitonic sort of candidates, emit exact top-K ----------
__global__ __launch_bounds__(1024) void k_sortk(
    const unsigned long long* __restrict__ cand, const int* __restrict__ cnt,
    float* __restrict__ tsc, int* __restrict__ tix)
{
    int b = blockIdx.x;
    int tid = threadIdx.x;
    __shared__ unsigned long long keys[CAND];
    int n = cnt[b * 16]; if (n > CAND) n = CAND;
    for (int i = tid; i < CAND; i += 1024)
        keys[i] = (i < n) ? cand[(size_t)b * CAND + i] : 0ull;
    __syncthreads();
    for (int sz = 2; sz <= CAND; sz <<= 1) {
        for (int st = sz >> 1; st > 0; st >>= 1) {
            for (int i = tid; i < CAND; i += 1024) {
                int j = i ^ st;
                if (j > i) {
                    unsigned long long a = keys[i], c = keys[j];
                    bool desc = ((i & sz) == 0);
                    if (desc ? (a < c) : (a > c)) { keys[i] = c; keys[j] = a; }
                }
            }
            __syncthreads();
        }
    }
    if (tid < KTOP) {
        unsigned long long key = keys[tid];
        tsc[b * KTOP + tid] = __uint_as_float((unsigned int)(key >> 32));
        tix[b * KTOP + tid] = (int)(0xFFFFFFFFu - (unsigned int)(key & 0xFFFFFFFFull));
    }
}

// ---- Kernel 3: decode boxes + exact class argmax for selected anchors -----------
__global__ __launch_bounds__(256) void k_decode(
    const float* __restrict__ c0, const float* __restrict__ c1,
    const float* __restrict__ c2, const float* __restrict__ c3,
    const float* __restrict__ c4,
    const float* __restrict__ r0, const float* __restrict__ r1,
    const float* __restrict__ r2, const float* __restrict__ r3,
    const float* __restrict__ r4,
    const float* __restrict__ t0, const float* __restrict__ t1,
    const float* __restrict__ t2, const float* __restrict__ t3,
    const float* __restrict__ t4,
    const float* __restrict__ q0, const float* __restrict__ q1,
    const float* __restrict__ q2, const float* __restrict__ q3,
    const float* __restrict__ q4,
    const int* __restrict__ tix, float* __restrict__ boxes, int* __restrict__ clstop)
{
    int g = blockIdx.x * 256 + threadIdx.x;
    if (g >= BATCH * KTOP) return;
    int b = g / KTOP;
    int idx = tix[g];
    int lvl, h, s, pos;
    levelOf(idx, lvl, h, s, pos);
    int y = pos / h, x = pos - y * h;
    int hh = h * h;
    const float* cp = (lvl == 0) ? c0 : (lvl == 1) ? c1 : (lvl == 2) ? c2 : (lvl == 3) ? c3 : c4;
    const float* rp = (lvl == 0) ? r0 : (lvl == 1) ? r1 : (lvl == 2) ? r2 : (lvl == 3) ? r3 : r4;
    const float* tp = (lvl == 0) ? t0 : (lvl == 1) ? t1 : (lvl == 2) ? t2 : (lvl == 3) ? t3 : t4;
    const float* qp = (lvl == 0) ? q0 : (lvl == 1) ? q1 : (lvl == 2) ? q2 : (lvl == 3) ? q3 : q4;
    int off = y * h + x;

    const float* cb = cp + (size_t)b * NCLS * hh + off;
    float bestc = -1e30f; int bc = 0;
    #pragma unroll
    for (int c = 0; c < NCLS; ++c) {
        float v = sigmoidf(cb[(size_t)c * hh]);
        if (v > bestc) { bestc = v; bc = c; }
    }
    clstop[g] = bc + 1;

    const float* tb = tp + (size_t)b * NTH * hh + off;
    float best = -1e30f; int bt = 0;
    #pragma unroll
    for (int c = 0; c < NTH; ++c) {
        float v = sigmoidf(tb[(size_t)c * hh]);
        if (v > best) { best = v; bt = c; }
    }
    float theta = (float)(bt + 1) * 10.0f + qp[(size_t)b * hh + off];

    const float* rb = rp + (size_t)b * 5 * hh + off;
    float fs = (float)s;
    float rr0 = rb[0] * fs;
    float rr1 = rb[(size_t)hh] * fs;
    float rr2 = rb[(size_t)2 * hh] * fs;
    float rr3 = rb[(size_t)3 * hh] * fs;
    float cx = (float)(x * s + (s >> 1));
    float cy = (float)(y * s + (s >> 1));
    float* op = boxes + (size_t)g * 5;
    op[0] = cx - rr0;
    op[1] = cy - rr1;
    op[2] = cx + rr2;
    op[3] = cy + rr3;
    op[4] = theta;
}

// ---- Kernel 4a: suppression bitmask — wave-uniform j-loop, broadcast LDS --------
__global__ __launch_bounds__(256) void k_mask(
    const float* __restrict__ boxes, unsigned long long* __restrict__ mask)
{
    const int b = blockIdx.x;
    const int by = blockIdx.y;
    __shared__ float bx1[1024], by1[1024], bx2[1024], by2[1024], bar[1024];
    for (int r = threadIdx.x; r < 1024; r += 256) {
        float x1 = 0.f, y1 = 0.f, x2 = 0.f, y2 = 0.f;
        if (r < KTOP) {
            const float* p = boxes + ((size_t)(b * KTOP + r)) * 5;
            x1 = p[0]; y1 = p[1]; x2 = p[2]; y2 = p[3];
        }
        bx1[r] = x1; by1[r] = y1; bx2[r] = x2; by2[r] = y2;
        bar[r] = fmaxf(x2 - x1, 0.0f) * fmaxf(y2 - y1, 0.0f);
    }
    __syncthreads();

    const int l  = threadIdx.x & 63;
    const int wv = threadIdx.x >> 6;
    const int i  = (by << 6) + l;
    const float x1 = bx1[i], y1 = by1[i], x2 = bx2[i], y2 = by2[i], ai = bar[i];

    for (int w = by + wv; w < NWORDS; w += 4) {
        const int j0 = w << 6;
        unsigned long long m = 0ull;
        #pragma unroll 8
        for (int jj = 0; jj < 64; ++jj) {
            const int j = j0 + jj;
            float iw = fminf(x2, bx2[j]) - fmaxf(x1, bx1[j]);
            iw = fmaxf(iw, 0.0f);
            float ih = fminf(y2, by2[j]) - fmaxf(y1, by1[j]);
            ih = fmaxf(ih, 0.0f);
            float inter = iw * ih;
            float u = ai + bar[j] - inter;
            float iou = inter / fmaxf(u, 1e-8f);
            unsigned long long bit = (iou > 0.3f && j > i) ? 1ull : 0ull;
            m |= bit << jj;
        }
        mask[(((size_t)b * 1024 + i) << 4) + w] = m;
    }
}

// ---- Kernel 4b: greedy NMS — sparse exact chain, prefetched rows, one wave ------
#define LOADROW(R, W) do {                                                          \
    const ulonglong2* rp2 = (const ulonglong2*)(mask +                              \
        (((size_t)b * 1024 + ((W) << 6) + l) << 4));                                \
    _Pragma("unroll")                                                               \
    for (int p = 0; p < 8; ++p) {                                                   \
        ulonglong2 v = rp2[p]; R[2 * p] = v.x; R[2 * p + 1] = v.y;                  \
    }                                                                               \
} while (0)

#define PROC(W, R) do {                                                             \
    const unsigned long long rowword = R[W];                                        \
    unsigned long long zr = __ballot(rowword == 0ull);                              \
    unsigned long long remw = sremv[W];                                             \
    unsigned long long pend = vw[W] & ~remw;                                        \
    unsigned long long keptm = 0ull;                                                \
    while (pend) {                                                                  \
        unsigned long long nzp = pend & ~zr;                                        \
        if (!nzp) { keptm |= pend; break; }                                         \
        int jj = __builtin_ctzll(nzp);                                              \
        unsigned long long low = (1ull << jj); low = (low << 1) - 1ull;             \
        keptm |= pend & low;                                                        \
        remw |= shfl_u64(rowword, jj);                                              \
        pend &= ~low; pend &= ~remw;                                                \
    }                                                                               \
    if (l == 0) skeep[W] = keptm;                                                   \
    if ((keptm >> l) & 1ull) {                                                      \
        _Pragma("unroll")                                                           \
        for (int w2 = (W) + 1; w2 < NWORDS; ++w2)                                   \
            if (R[w2]) atomicOr64Shared(&sremv[w2], R[w2]);                         \
    }                                                                               \
} while (0)

__global__ __launch_bounds__(64) void k_nms(
    const unsigned long long* __restrict__ mask,   // [b][1024][16]
    const float* __restrict__ tsc, const int* __restrict__ clstop,
    const float* __restrict__ boxes, float* __restrict__ out)
{
    const int b = blockIdx.x;
    const int l = threadIdx.x;
    __shared__ unsigned long long sremv[NWORDS];
    __shared__ unsigned long long skeep[NWORDS];

    if (l < NWORDS) sremv[l] = 0ull;   // single wave: in-order LDS, no barrier

    unsigned long long vw[NWORDS];
    #pragma unroll
    for (int w = 0; w < NWORDS; ++w) {
        int i = (w << 6) + l;
        bool v = (i < KTOP) && (tsc[b * KTOP + i] >= 0.05f);
        vw[w] = __ballot(v);
    }

    unsigned long long rowA[NWORDS], rowB[NWORDS];
    LOADROW(rowA, 0);
    LOADROW(rowB, 1);   PROC(0, rowA);
    LOADROW(rowA, 2);   PROC(1, rowB);
    LOADROW(rowB, 3);   PROC(2, rowA);
    LOADROW(rowA, 4);   PROC(3, rowB);
    LOADROW(rowB, 5);   PROC(4, rowA);
    LOADROW(rowA, 6);   PROC(5, rowB);
    LOADROW(rowB, 7);   PROC(6, rowA);
    LOADROW(rowA, 8);   PROC(7, rowB);
    LOADROW(rowB, 9);   PROC(8, rowA);
    LOADROW(rowA, 10);  PROC(9, rowB);
    LOADROW(rowB, 11);  PROC(10, rowA);
    LOADROW(rowA, 12);  PROC(11, rowB);
    LOADROW(rowB, 13);  PROC(12, rowA);
    LOADROW(rowA, 14);  PROC(13, rowB);
    LOADROW(rowB, 15);  PROC(14, rowA);
    PROC(15, rowB);

    // fused masked output write
    #pragma unroll
    for (int w = 0; w < NWORDS; ++w) {
        int i = (w << 6) + l;
        if (i < KTOP) {
            int g = b * KTOP + i;
            float fk = (float)((skeep[w] >> l) & 1ull);
            out[g] = tsc[g] * fk;
            out[BATCH * KTOP + g] = (float)clstop[g] * fk;
            const float* bp = boxes + (size_t)g * 5;
            float* op = out + 2 * BATCH * KTOP + (size_t)g * 5;
            op[0] = bp[0] * fk;
            op[1] = bp[1] * fk;
            op[2] = bp[2] * fk;
            op[3] = bp[3] * fk;
            op[4] = bp[4] * fk;
        }
    }
}

extern "C" void kernel_launch(void* const* d_in, const int* in_sizes, int n_in,
                              void* d_out, int out_size, void* d_ws, size_t ws_size,
                              hipStream_t stream) {
    const float* c0 = (const float*)d_in[0];
    const float* c1 = (const float*)d_in[1];
    const float* c2 = (const float*)d_in[2];
    const float* c3 = (const float*)d_in[3];
    const float* c4 = (const float*)d_in[4];
    const float* r0 = (const float*)d_in[5];
    const float* r1 = (const float*)d_in[6];
    const float* r2 = (const float*)d_in[7];
    const float* r3 = (const float*)d_in[8];
    const float* r4 = (const float*)d_in[9];
    const float* t0 = (const float*)d_in[10];
    const float* t1 = (const float*)d_in[11];
    const float* t2 = (const float*)d_in[12];
    const float* t3 = (const float*)d_in[13];
    const float* t4 = (const float*)d_in[14];
    const float* q0 = (const float*)d_in[15];
    const float* q1 = (const float*)d_in[16];
    const float* q2 = (const float*)d_in[17];
    const float* q3 = (const float*)d_in[18];
    const float* q4 = (const float*)d_in[19];

    // Workspace layout, total 5,753,920 B. Aliases safe by stream order:
    //   hist (k_scores→k_findT) aliases mask (k_mask→k_nms)   [findT before mask]
    //   cand (k_compact→k_sortk) aliases boxes (k_decode→...) [sortk before decode]
    char* ws = (char*)d_ws;
    float*              scores  = (float*)(ws + 0);          // 3,142,656
    float*              tsc     = (float*)(ws + 3142656);    //    64,000
    int*                tix     = (int*)(ws + 3206656);      //    64,000
    float*              boxes   = (float*)(ws + 3270656);    //   320,000
    unsigned long long* cand    = (unsigned long long*)(ws + 3270656); // 262,144 alias
    int*                clstop  = (int*)(ws + 3590656);      //    64,000
    unsigned long long* mask    = (unsigned long long*)(ws + 3654656); // 2,097,152
    unsigned int*       hist    = (unsigned int*)(ws + 3654656);       // alias
    int*                tcnt    = (int*)(ws + 5751808);      //     1,024 (16 x 64B)
    int*                tbin    = (int*)(ws + 5752832);      //        64
    float*              out     = (float*)d_out;

    // zero hist + tcnt (2,098,176 B = 131,136 uint4) with our own kernel:
    // the runtime's fillBufferAligned ran this at 52 GB/s (~40 us).
    const int n4 = 2098176 / 16;
    k_zero<<<(n4 + 255) / 256, 256, 0, stream>>>((uint4*)(ws + 3654656), n4);

    k_scores<<<dim3(24, BATCH), 256, 0, stream>>>(
        c0, c1, c2, c3, c4, scores, hist);
    k_findT<<<BATCH, 256, 0, stream>>>(hist, tbin);
    k_compact<<<dim3(48, BATCH), 256, 0, stream>>>(scores, tbin, tcnt, cand);
    k_sortk<<<BATCH, 1024, 0, stream>>>(cand, tcnt, tsc, tix);
    k_decode<<<(BATCH * KTOP + 255) / 256, 256, 0, stream>>>(
        c0, c1, c2, c3, c4,
        r0, r1, r2, r3, r4, t0, t1, t2, t3, t4, q0, q1, q2, q3, q4,
        tix, boxes, clstop);
    k_mask<<<dim3(BATCH, 16), 256, 0, stream>>>(boxes, mask);
    k_nms<<<BATCH, 64, 0, stream>>>(mask, tsc, clstop, boxes, out);
}

// Round 12
// 112.087 us; speedup vs baseline: 1.6048x; 1.0919x over previous
//
#include <hip/hip_runtime.h>
#include <stdint.h>

#define NCLS   15
#define NTH    18
#define BATCH  16
#define NANCH  49104
#define KTOP   1000
#define NWORDS 16   // 16*64 = 1024 >= 1000
#define NBIN   32768
#define BSHIFT 15
#define CAND   2048

__device__ __forceinline__ float sigmoidf(float x) {
    return 1.0f / (1.0f + expf(-x));
}

__device__ __forceinline__ void levelOf(int i, int& lvl, int& h, int& s, int& pos) {
    if (i < 36864)      { lvl = 0; h = 192; s = 8;   pos = i; }
    else if (i < 46080) { lvl = 1; h = 96;  s = 16;  pos = i - 36864; }
    else if (i < 48384) { lvl = 2; h = 48;  s = 32;  pos = i - 46080; }
    else if (i < 48960) { lvl = 3; h = 24;  s = 64;  pos = i - 48384; }
    else                { lvl = 4; h = 12;  s = 128; pos = i - 48960; }
}

__device__ __forceinline__ unsigned long long shfl_u64(unsigned long long v, int src) {
    int lo = __shfl((int)(unsigned int)(v & 0xFFFFFFFFull), src);
    int hi = __shfl((int)(unsigned int)(v >> 32), src);
    return ((unsigned long long)(unsigned int)hi << 32) | (unsigned long long)(unsigned int)lo;
}

__device__ __forceinline__ void atomicOr64Shared(unsigned long long* p, unsigned long long v) {
    unsigned int* q = (unsigned int*)p;
    unsigned int lo = (unsigned int)v;
    unsigned int hi = (unsigned int)(v >> 32);
    if (lo) atomicOr(q, lo);
    if (hi) atomicOr(q + 1, hi);
}

// ---- Kernel 1: per-anchor score = sigmoid(max logit), float4, pure stream -------
__global__ __launch_bounds__(256) void k_scores(
    const float* __restrict__ c0, const float* __restrict__ c1,
    const float* __restrict__ c2, const float* __restrict__ c3,
    const float* __restrict__ c4,
    float* __restrict__ scores)
{
    int g4 = blockIdx.x * 256 + threadIdx.x;
    if (g4 >= BATCH * NANCH / 4) return;
    int g = g4 * 4;
    int b = g / NANCH;
    int i = g - b * NANCH;          // multiple of 4; level boundaries are too
    int lvl, h, s, pos;
    levelOf(i, lvl, h, s, pos);
    int hh = h * h;
    const float* cp = (lvl == 0) ? c0 : (lvl == 1) ? c1 : (lvl == 2) ? c2
                      : (lvl == 3) ? c3 : c4;
    const float* base = cp + (size_t)b * NCLS * hh + pos;
    float4 mx = make_float4(-1e30f, -1e30f, -1e30f, -1e30f);
    #pragma unroll
    for (int c = 0; c < NCLS; ++c) {
        float4 v = *(const float4*)(base + (size_t)c * hh);
        mx.x = fmaxf(mx.x, v.x); mx.y = fmaxf(mx.y, v.y);
        mx.z = fmaxf(mx.z, v.z); mx.w = fmaxf(mx.w, v.w);
    }
    float4 sc = make_float4(sigmoidf(mx.x), sigmoidf(mx.y),
                            sigmoidf(mx.z), sigmoidf(mx.w));
    *(float4*)(scores + g) = sc;
}

// ---- Kernel 2: fused top-K select (hist + threshold + compact + sort), 1 blk/b --
__global__ __launch_bounds__(1024) void k_select(
    const float* __restrict__ scores,
    float* __restrict__ tsc, int* __restrict__ tix)
{
    const int b   = blockIdx.x;
    const int tid = threadIdx.x;
    __shared__ unsigned long long smem[NBIN / 4];   // 64 KB: hist, later keys
    __shared__ unsigned int csum[1024];
    __shared__ int s_c, s_T, s_cnt;
    unsigned int* lh = (unsigned int*)smem;          // 16384 packed-16-bit words
    unsigned long long* keys = smem;                 // 2048 u64 (aliases lh)

    // 1) zero hist
    for (int i = tid; i < NBIN / 2; i += 1024) lh[i] = 0u;
    if (tid == 0) { s_c = 0; s_T = 0; s_cnt = 0; }
    __syncthreads();

    // 2) build per-batch histogram (16-bit packed counts; max 49104 < 65536)
    const float4* sv = (const float4*)(scores + (size_t)b * NANCH);
    for (int f4 = tid; f4 < NANCH / 4; f4 += 1024) {
        float4 v = sv[f4];
        unsigned int bin;
        bin = __float_as_uint(v.x) >> BSHIFT;
        atomicAdd(&lh[bin >> 1], 1u << ((bin & 1) << 4));
        bin = __float_as_uint(v.y) >> BSHIFT;
        atomicAdd(&lh[bin >> 1], 1u << ((bin & 1) << 4));
        bin = __float_as_uint(v.z) >> BSHIFT;
        atomicAdd(&lh[bin >> 1], 1u << ((bin & 1) << 4));
        bin = __float_as_uint(v.w) >> BSHIFT;
        atomicAdd(&lh[bin >> 1], 1u << ((bin & 1) << 4));
    }
    __syncthreads();

    // 3) chunk sums: thread t owns bins [32t, 32t+32) = lh words [16t, 16t+16)
    unsigned int s = 0;
    #pragma unroll
    for (int k = 0; k < 16; ++k) {
        unsigned int w = lh[tid * 16 + k];
        s += (w & 0xFFFFu) + (w >> 16);
    }
    csum[tid] = s;
    __syncthreads();
    // inclusive suffix scan over 1024 chunk sums
    for (int d = 1; d < 1024; d <<= 1) {
        unsigned int add = (tid + d < 1024) ? csum[tid + d] : 0u;
        __syncthreads();
        csum[tid] += add;
        __syncthreads();
    }
    // largest chunk c with suffix >= KTOP (unique; exists since csum[0]=49104)
    if (csum[tid] >= (unsigned)KTOP &&
        (tid == 1023 || csum[tid + 1] < (unsigned)KTOP))
        s_c = tid;
    __syncthreads();
    const int c = s_c;
    const unsigned int hi = (c < 1023) ? csum[c + 1] : 0u;

    // 4) threshold bin within chunk c: wave-level suffix scan over 32 bins
    if (tid < 64) {
        unsigned int cnt = 0;
        if (tid < 32) {
            int bin = c * 32 + tid;
            cnt = (lh[bin >> 1] >> ((bin & 1) << 4)) & 0xFFFFu;
        }
        unsigned int suf = cnt;
        #pragma unroll
        for (int d = 1; d < 32; d <<= 1) {
            unsigned int o = __shfl_down(suf, d);
            if (tid + d < 32) suf += o;
        }
        unsigned int nxt = __shfl_down(suf, 1);
        if (tid < 32) {
            if (hi + suf >= (unsigned)KTOP &&
                (tid == 31 || hi + nxt < (unsigned)KTOP))
                s_T = c * 32 + tid;
        }
    }
    __syncthreads();
    const int T = s_T;

    // 5) compact candidates into LDS keys (order irrelevant — sorted below)
    keys[tid] = 0ull; keys[tid + 1024] = 0ull;       // hist dead; alias safe
    __syncthreads();
    for (int f4 = tid; f4 < NANCH / 4; f4 += 1024) {
        float4 v = sv[f4];
        unsigned int bits[4] = { __float_as_uint(v.x), __float_as_uint(v.y),
                                 __float_as_uint(v.z), __float_as_uint(v.w) };
        #pragma unroll
        for (int k = 0; k < 4; ++k) {
            if ((int)(bits[k] >> BSHIFT) >= T) {
                int p = atomicAdd(&s_cnt, 1);
                if (p < CAND) {
                    unsigned int idx = 4u * (unsigned int)f4 + (unsigned int)k;
                    keys[p] = ((unsigned long long)bits[k] << 32) |
                              (unsigned long long)(0xFFFFFFFFu - idx);
                }
            }
        }
    }
    __syncthreads();

    // 6) bitonic sort descending over 2048 keys (pads=0 sort last)
    for (int sz = 2; sz <= CAND; sz <<= 1) {
        for (int st = sz >> 1; st > 0; st >>= 1) {
            for (int i = tid; i < CAND; i += 1024) {
                int j = i ^ st;
                if (j > i) {
                    unsigned long long a = keys[i], cc = keys[j];
                    bool desc = ((i & sz) == 0);
                    if (desc ? (a < cc) : (a > cc)) { keys[i] = cc; keys[j] = a; }
                }
            }
            __syncthreads();
        }
    }

    if (tid < KTOP) {
        unsigned long long key = keys[tid];
        tsc[b * KTOP + tid] = __uint_as_float((unsigned int)(key >> 32));
        tix[b * KTOP + tid] = (int)(0xFFFFFFFFu - (unsigned int)(key & 0xFFFFFFFFull));
    }
}

// ---- Kernel 3: decode boxes + exact class argmax for selected anchors -----------
__global__ __launch_bounds__(256) void k_decode(
    const float* __restrict__ c0, const float* __restrict__ c1,
    const float* __restrict__ c2, const float* __restrict__ c3,
    const float* __restrict__ c4,
    const float* __restrict__ r0, const float* __restrict__ r1,
    const float* __restrict__ r2, const float* __restrict__ r3,
    const float* __restrict__ r4,
    const float* __restrict__ t0, const float* __restrict__ t1,
    const float* __restrict__ t2, const float* __restrict__ t3,
    const float* __restrict__ t4,
    const float* __restrict__ q0, const float* __restrict__ q1,
    const float* __restrict__ q2, const float* __restrict__ q3,
    const float* __restrict__ q4,
    const int* __restrict__ tix, float* __restrict__ boxes, int* __restrict__ clstop)
{
    int g = blockIdx.x * 256 + threadIdx.x;
    if (g >= BATCH * KTOP) return;
    int b = g / KTOP;
    int idx = tix[g];
    int lvl, h, s, pos;
    levelOf(idx, lvl, h, s, pos);
    int y = pos / h, x = pos - y * h;
    int hh = h * h;
    const float* cp = (lvl == 0) ? c0 : (lvl == 1) ? c1 : (lvl == 2) ? c2 : (lvl == 3) ? c3 : c4;
    const float* rp = (lvl == 0) ? r0 : (lvl == 1) ? r1 : (lvl == 2) ? r2 : (lvl == 3) ? r3 : r4;
    const float* tp = (lvl == 0) ? t0 : (lvl == 1) ? t1 : (lvl == 2) ? t2 : (lvl == 3) ? t3 : t4;
    const float* qp = (lvl == 0) ? q0 : (lvl == 1) ? q1 : (lvl == 2) ? q2 : (lvl == 3) ? q3 : q4;
    int off = y * h + x;

    const float* cb = cp + (size_t)b * NCLS * hh + off;
    float bestc = -1e30f; int bc = 0;
    #pragma unroll
    for (int c = 0; c < NCLS; ++c) {
        float v = sigmoidf(cb[(size_t)c * hh]);
        if (v > bestc) { bestc = v; bc = c; }
    }
    clstop[g] = bc + 1;

    const float* tb = tp + (size_t)b * NTH * hh + off;
    float best = -1e30f; int bt = 0;
    #pragma unroll
    for (int c = 0; c < NTH; ++c) {
        float v = sigmoidf(tb[(size_t)c * hh]);
        if (v > best) { best = v; bt = c; }
    }
    float theta = (float)(bt + 1) * 10.0f + qp[(size_t)b * hh + off];

    const float* rb = rp + (size_t)b * 5 * hh + off;
    float fs = (float)s;
    float rr0 = rb[0] * fs;
    float rr1 = rb[(size_t)hh] * fs;
    float rr2 = rb[(size_t)2 * hh] * fs;
    float rr3 = rb[(size_t)3 * hh] * fs;
    float cx = (float)(x * s + (s >> 1));
    float cy = (float)(y * s + (s >> 1));
    float* op = boxes + (size_t)g * 5;
    op[0] = cx - rr0;
    op[1] = cy - rr1;
    op[2] = cx + rr2;
    op[3] = cy + rr3;
    op[4] = theta;
}

// ---- Kernel 4a: suppression bitmask — wave-uniform j-loop, broadcast LDS --------
__global__ __launch_bounds__(256) void k_mask(
    const float* __restrict__ boxes, unsigned long long* __restrict__ mask)
{
    const int b = blockIdx.x;
    const int by = blockIdx.y;
    __shared__ float bx1[1024], by1[1024], bx2[1024], by2[1024], bar[1024];
    for (int r = threadIdx.x; r < 1024; r += 256) {
        float x1 = 0.f, y1 = 0.f, x2 = 0.f, y2 = 0.f;
        if (r < KTOP) {
            const float* p = boxes + ((size_t)(b * KTOP + r)) * 5;
            x1 = p[0]; y1 = p[1]; x2 = p[2]; y2 = p[3];
        }
        bx1[r] = x1; by1[r] = y1; bx2[r] = x2; by2[r] = y2;
        bar[r] = fmaxf(x2 - x1, 0.0f) * fmaxf(y2 - y1, 0.0f);
    }
    __syncthreads();

    const int l  = threadIdx.x & 63;
    const int wv = threadIdx.x >> 6;
    const int i  = (by << 6) + l;
    const float x1 = bx1[i], y1 = by1[i], x2 = bx2[i], y2 = by2[i], ai = bar[i];

    for (int w = by + wv; w < NWORDS; w += 4) {
        const int j0 = w << 6;
        unsigned long long m = 0ull;
        #pragma unroll 8
        for (int jj = 0; jj < 64; ++jj) {
            const int j = j0 + jj;
            float iw = fminf(x2, bx2[j]) - fmaxf(x1, bx1[j]);
            iw = fmaxf(iw, 0.0f);
            float ih = fminf(y2, by2[j]) - fmaxf(y1, by1[j]);
            ih = fmaxf(ih, 0.0f);
            float inter = iw * ih;
            float u = ai + bar[j] - inter;
            float iou = inter / fmaxf(u, 1e-8f);
            unsigned long long bit = (iou > 0.3f && j > i) ? 1ull : 0ull;
            m |= bit << jj;
        }
        mask[(((size_t)b * 1024 + i) << 4) + w] = m;
    }
}

// ---- Kernel 4b: greedy NMS — sparse exact chain, prefetched rows, one wave ------
#define LOADROW(R, W) do {                                                          \
    const ulonglong2* rp2 = (const ulonglong2*)(mask +                              \
        (((size_t)b * 1024 + ((W) << 6) + l) << 4));                                \
    _Pragma("unroll")                                                               \
    for (int p = 0; p < 8; ++p) {                                                   \
        ulonglong2 v = rp2[p]; R[2 * p] = v.x; R[2 * p + 1] = v.y;                  \
    }                                                                               \
} while (0)

#define PROC(W, R) do {                                                             \
    const unsigned long long rowword = R[W];                                        \
    unsigned long long zr = __ballot(rowword == 0ull);                              \
    unsigned long long remw = sremv[W];                                             \
    unsigned long long pend = vw[W] & ~remw;                                        \
    unsigned long long keptm = 0ull;                                                \
    while (pend) {                                                                  \
        unsigned long long nzp = pend & ~zr;                                        \
        if (!nzp) { keptm |= pend; break; }                                         \
        int jj = __builtin_ctzll(nzp);                                              \
        unsigned long long low = (1ull << jj); low = (low << 1) - 1ull;             \
        keptm |= pend & low;                                                        \
        remw |= shfl_u64(rowword, jj);                                              \
        pend &= ~low; pend &= ~remw;                                                \
    }                                                                               \
    if (l == 0) skeep[W] = keptm;                                                   \
    if ((keptm >> l) & 1ull) {                                                      \
        _Pragma("unroll")                                                           \
        for (int w2 = (W) + 1; w2 < NWORDS; ++w2)                                   \
            if (R[w2]) atomicOr64Shared(&sremv[w2], R[w2]);                         \
    }                                                                               \
} while (0)

__global__ __launch_bounds__(64) void k_nms(
    const unsigned long long* __restrict__ mask,   // [b][1024][16]
    const float* __restrict__ tsc, const int* __restrict__ clstop,
    const float* __restrict__ boxes, float* __restrict__ out)
{
    const int b = blockIdx.x;
    const int l = threadIdx.x;
    __shared__ unsigned long long sremv[NWORDS];
    __shared__ unsigned long long skeep[NWORDS];

    if (l < NWORDS) sremv[l] = 0ull;   // single wave: in-order LDS, no barrier

    unsigned long long vw[NWORDS];
    #pragma unroll
    for (int w = 0; w < NWORDS; ++w) {
        int i = (w << 6) + l;
        bool v = (i < KTOP) && (tsc[b * KTOP + i] >= 0.05f);
        vw[w] = __ballot(v);
    }

    unsigned long long rowA[NWORDS], rowB[NWORDS];
    LOADROW(rowA, 0);
    LOADROW(rowB, 1);   PROC(0, rowA);
    LOADROW(rowA, 2);   PROC(1, rowB);
    LOADROW(rowB, 3);   PROC(2, rowA);
    LOADROW(rowA, 4);   PROC(3, rowB);
    LOADROW(rowB, 5);   PROC(4, rowA);
    LOADROW(rowA, 6);   PROC(5, rowB);
    LOADROW(rowB, 7);   PROC(6, rowA);
    LOADROW(rowA, 8);   PROC(7, rowB);
    LOADROW(rowB, 9);   PROC(8, rowA);
    LOADROW(rowA, 10);  PROC(9, rowB);
    LOADROW(rowB, 11);  PROC(10, rowA);
    LOADROW(rowA, 12);  PROC(11, rowB);
    LOADROW(rowB, 13);  PROC(12, rowA);
    LOADROW(rowA, 14);  PROC(13, rowB);
    LOADROW(rowB, 15);  PROC(14, rowA);
    PROC(15, rowB);

    // fused masked output write
    #pragma unroll
    for (int w = 0; w < NWORDS; ++w) {
        int i = (w << 6) + l;
        if (i < KTOP) {
            int g = b * KTOP + i;
            float fk = (float)((skeep[w] >> l) & 1ull);
            out[g] = tsc[g] * fk;
            out[BATCH * KTOP + g] = (float)clstop[g] * fk;
            const float* bp = boxes + (size_t)g * 5;
            float* op = out + 2 * BATCH * KTOP + (size_t)g * 5;
            op[0] = bp[0] * fk;
            op[1] = bp[1] * fk;
            op[2] = bp[2] * fk;
            op[3] = bp[3] * fk;
            op[4] = bp[4] * fk;
        }
    }
}

extern "C" void kernel_launch(void* const* d_in, const int* in_sizes, int n_in,
                              void* d_out, int out_size, void* d_ws, size_t ws_size,
                              hipStream_t stream) {
    const float* c0 = (const float*)d_in[0];
    const float* c1 = (const float*)d_in[1];
    const float* c2 = (const float*)d_in[2];
    const float* c3 = (const float*)d_in[3];
    const float* c4 = (const float*)d_in[4];
    const float* r0 = (const float*)d_in[5];
    const float* r1 = (const float*)d_in[6];
    const float* r2 = (const float*)d_in[7];
    const float* r3 = (const float*)d_in[8];
    const float* r4 = (const float*)d_in[9];
    const float* t0 = (const float*)d_in[10];
    const float* t1 = (const float*)d_in[11];
    const float* t2 = (const float*)d_in[12];
    const float* t3 = (const float*)d_in[13];
    const float* t4 = (const float*)d_in[14];
    const float* q0 = (const float*)d_in[15];
    const float* q1 = (const float*)d_in[16];
    const float* q2 = (const float*)d_in[17];
    const float* q3 = (const float*)d_in[18];
    const float* q4 = (const float*)d_in[19];

    // Workspace layout, total 5,751,808 B. No aliases, no zeroing needed:
    // hist/count/candidates now live in k_select's LDS; mask's unread
    // lower-triangle words are never consumed by k_nms.
    char* ws = (char*)d_ws;
    float*              scores  = (float*)(ws + 0);          // 3,142,656
    float*              tsc     = (float*)(ws + 3142656);    //    64,000
    int*                tix     = (int*)(ws + 3206656);      //    64,000
    float*              boxes   = (float*)(ws + 3270656);    //   320,000
    int*                clstop  = (int*)(ws + 3590656);      //    64,000
    unsigned long long* mask    = (unsigned long long*)(ws + 3654656); // 2,097,152
    float*              out     = (float*)d_out;

    k_scores<<<(BATCH * NANCH / 4 + 255) / 256, 256, 0, stream>>>(
        c0, c1, c2, c3, c4, scores);
    k_select<<<BATCH, 1024, 0, stream>>>(scores, tsc, tix);
    k_decode<<<(BATCH * KTOP + 255) / 256, 256, 0, stream>>>(
        c0, c1, c2, c3, c4,
        r0, r1, r2, r3, r4, t0, t1, t2, t3, t4, q0, q1, q2, q3, q4,
        tix, boxes, clstop);
    k_mask<<<dim3(BATCH, 16), 256, 0, stream>>>(boxes, mask);
    k_nms<<<BATCH, 64, 0, stream>>>(mask, tsc, clstop, boxes, out);
}